// Round 5
// baseline (876.524 us; speedup 1.0000x reference)
//
#include <hip/hip_runtime.h>
#include <math.h>
#include <stdint.h>

#define NN 100000
#define NE 1600000
#define INC 128
#define DIM 64
#define EPS 1e-5f
#define SB 512   // stats blocks inside fused stats+hist kernel
#define NBK ((NN + 127) / 128)   // 782 scatter buckets

// fused: blocks [0,SB) do X stats (C=128) in f64; blocks [SB,...) do dst histogram
__global__ __launch_bounds__(256) void stats_hist_kernel(const float* __restrict__ X,
        const int* __restrict__ dst, int* __restrict__ counts,
        double* __restrict__ sum_out, double* __restrict__ sq_out) {
    __shared__ double ls[256], lq[256];
    if (blockIdx.x < SB) {
        int c  = threadIdx.x & 127;
        int rl = threadIdx.x >> 7;           // 2 rows per block step
        int row = blockIdx.x * 2 + rl;
        const int rstride = SB * 2;
        double s = 0.0, q = 0.0;
        for (int r = row; r < NN; r += rstride) {
            double v = (double)X[(size_t)r * INC + c];
            s += v; q += v * v;
        }
        ls[threadIdx.x] = s; lq[threadIdx.x] = q;
        __syncthreads();
        if (rl == 0) {
            s += ls[128 + c]; q += lq[128 + c];
            atomicAdd(&sum_out[c], s);
            atomicAdd(&sq_out[c], q);
        }
    } else {
        int e = (blockIdx.x - SB) * 256 + threadIdx.x;
        if (e < NE) atomicAdd(&counts[dst[e]], 1);
    }
}

// BN scale/shift from f64 stats (device helper, computed redundantly per block)
__device__ inline void bn_fold(int t, int C, const double* dsum, const double* dsq,
                               const float* g, const float* b, float* sc_s, float* sh_s) {
    if (t < C) {
        double m = dsum[t] / (double)NN;
        double v = dsq[t] / (double)NN - m * m;
        double sc = (double)g[t] / sqrt(v + (double)EPS);
        sc_s[t] = (float)sc;
        sh_s[t] = (float)((double)b[t] - m * sc);
    }
}

// ---------------- CSR build: scan ----------------
__global__ __launch_bounds__(1024) void scan1_kernel(const int* __restrict__ counts,
                                                     int* __restrict__ offs, int* __restrict__ bsums) {
    __shared__ int tmp[2][1024];
    int t = threadIdx.x;
    int g = blockIdx.x * 1024 + t;
    int v = (g < NN) ? counts[g] : 0;
    tmp[0][t] = v;
    __syncthreads();
    int pin = 0;
    for (int d = 1; d < 1024; d <<= 1) {
        int x = tmp[pin][t] + ((t >= d) ? tmp[pin][t - d] : 0);
        tmp[pin ^ 1][t] = x;
        pin ^= 1;
        __syncthreads();
    }
    int incl = tmp[pin][t];
    if (g < NN) offs[g] = incl - v;
    if (t == 1023) bsums[blockIdx.x] = incl;
}

__global__ __launch_bounds__(128) void scan2_kernel(int* __restrict__ bsums, int nb) {
    __shared__ int tmp[2][128];
    int t = threadIdx.x;
    int v = (t < nb) ? bsums[t] : 0;
    tmp[0][t] = v;
    __syncthreads();
    int pin = 0;
    for (int d = 1; d < 128; d <<= 1) {
        int x = tmp[pin][t] + ((t >= d) ? tmp[pin][t - d] : 0);
        tmp[pin ^ 1][t] = x;
        pin ^= 1;
        __syncthreads();
    }
    if (t < nb) bsums[t] = tmp[pin][t] - v;
}

// final offsets + bucket cursors (bucket b = nodes [b*128, b*128+128))
__global__ __launch_bounds__(256) void scan3_kernel(int* __restrict__ offs, const int* __restrict__ bsums,
                                                    int* __restrict__ bcur) {
    int g = blockIdx.x * 256 + threadIdx.x;
    if (g < NN) {
        int o = offs[g] + bsums[g >> 10];
        offs[g] = o;
        if ((g & 127) == 0) bcur[g >> 7] = o;
    }
    if (g == 0) offs[NN] = NE;
}

// ---------------- bucketed scatter ----------------
// pass A: bin records into bucket regions (contiguous unions of node segments)
__global__ __launch_bounds__(256) void scatterA_kernel(const int* __restrict__ src, const int* __restrict__ dst,
        const float* __restrict__ ea, int* __restrict__ bcur,
        int2* __restrict__ stage_se, int* __restrict__ stage_d) {
    int e = blockIdx.x * 256 + threadIdx.x;
    if (e >= NE) return;
    int d = dst[e];
    int pos = atomicAdd(&bcur[d >> 7], 1);
    stage_se[pos] = make_int2(src[e], __float_as_int(ea[e]));
    stage_d[pos] = d;
}

// pass B: one block per bucket, place records at exact CSR positions via LDS cursors
__global__ __launch_bounds__(256) void scatterB_kernel(const int* __restrict__ offs,
        const int2* __restrict__ stage_se, const int* __restrict__ stage_d,
        int2* __restrict__ src_ea) {
    __shared__ int lcur[128];
    int b = blockIdx.x;
    int nb = b << 7;
    int t = threadIdx.x;
    if (t < 128) lcur[t] = (nb + t < NN) ? offs[nb + t] : 0;
    __syncthreads();
    int rbeg = offs[nb];
    int rend = offs[min(nb + 128, NN)];
    for (int j = rbeg + t; j < rend; j += 256) {
        int d = stage_d[j];
        int2 se = stage_se[j];
        int pos = atomicAdd(&lcur[d - nb], 1);
        src_ea[pos] = se;
    }
}

// ---------------- fused layer 0: BN-fold + gather-agg (half-wave) + GEMM + tanh + stats ----------------
// 32 nodes per 512-thread block. t1 -> t1_ws [NN][64] packed; per-channel stats -> dsum0/dsq0
__global__ __launch_bounds__(512) void gine0_kernel(const float* __restrict__ X,
        const int* __restrict__ offs, const int2* __restrict__ src_ea,
        const double* __restrict__ dsum, const double* __restrict__ dsq,
        const float* __restrict__ g, const float* __restrict__ b,
        const float* __restrict__ We, const float* __restrict__ be,
        const float* __restrict__ W, const float* __restrict__ bvec,
        float* __restrict__ t1_ws, double* __restrict__ dsum0, double* __restrict__ dsq0) {
    __shared__ __align__(16) float u_s[32][INC + 4];   // 16.9 KB
    __shared__ __align__(16) float w_s[DIM][INC + 4];  // 33.8 KB (reused for stats reduce)
    __shared__ float sc_s[INC], sh_s[INC];
    const int t = threadIdx.x;
    const int row0 = blockIdx.x * 32;
    bn_fold(t, INC, dsum, dsq, g, b, sc_s, sh_s);
    for (int i = t; i < INC * DIM; i += 512) {
        int k = i >> 6, c = i & 63;
        w_s[c][k] = W[i];
    }
    __syncthreads();
    // gather: 8 waves x 4 nodes; within a wave, halves process 2 edges at a time
    const int wid = t >> 6, l = t & 63;
    const int half = l >> 5;
    const int c4 = (l & 31) * 4;
    float4 sc = *(const float4*)(sc_s + c4);
    float4 sh = *(const float4*)(sh_s + c4);
    float4 wv = *(const float4*)(We + c4);
    float4 bv = *(const float4*)(be + c4);
    for (int nn = 0; nn < 4; ++nn) {
        int r = wid * 4 + nn;
        int n = row0 + r;
        float a0 = 0.f, a1 = 0.f, a2 = 0.f, a3 = 0.f;
        if (n < NN) {
            int beg = offs[n], end = offs[n + 1];
            for (int base = beg; base < end; base += 64) {
                int j = base + l;
                int2 p = (j < end) ? src_ea[j] : make_int2(0, 0);
                float avf = __int_as_float(p.y);
                int cnt = min(64, end - base);
                int tt = 0;
                for (; tt + 4 <= cnt; tt += 4) {
                    int e0 = tt + half, e1 = tt + 2 + half;
                    int s0 = __shfl(p.x, e0), s1 = __shfl(p.x, e1);
                    float av0 = __shfl(avf, e0), av1 = __shfl(avf, e1);
                    float4 x0 = *(const float4*)(X + (size_t)s0 * INC + c4);
                    float4 x1 = *(const float4*)(X + (size_t)s1 * INC + c4);
                    a0 += fmaxf(fmaf(x0.x, sc.x, sh.x) + fmaf(av0, wv.x, bv.x), 0.f);
                    a1 += fmaxf(fmaf(x0.y, sc.y, sh.y) + fmaf(av0, wv.y, bv.y), 0.f);
                    a2 += fmaxf(fmaf(x0.z, sc.z, sh.z) + fmaf(av0, wv.z, bv.z), 0.f);
                    a3 += fmaxf(fmaf(x0.w, sc.w, sh.w) + fmaf(av0, wv.w, bv.w), 0.f);
                    a0 += fmaxf(fmaf(x1.x, sc.x, sh.x) + fmaf(av1, wv.x, bv.x), 0.f);
                    a1 += fmaxf(fmaf(x1.y, sc.y, sh.y) + fmaf(av1, wv.y, bv.y), 0.f);
                    a2 += fmaxf(fmaf(x1.z, sc.z, sh.z) + fmaf(av1, wv.z, bv.z), 0.f);
                    a3 += fmaxf(fmaf(x1.w, sc.w, sh.w) + fmaf(av1, wv.w, bv.w), 0.f);
                }
                for (; tt < cnt; tt += 2) {
                    int e0 = tt + half;
                    int es = min(e0, cnt - 1);
                    int s0 = __shfl(p.x, es);
                    float av0 = __shfl(avf, es);
                    if (e0 < cnt) {
                        float4 x0 = *(const float4*)(X + (size_t)s0 * INC + c4);
                        a0 += fmaxf(fmaf(x0.x, sc.x, sh.x) + fmaf(av0, wv.x, bv.x), 0.f);
                        a1 += fmaxf(fmaf(x0.y, sc.y, sh.y) + fmaf(av0, wv.y, bv.y), 0.f);
                        a2 += fmaxf(fmaf(x0.z, sc.z, sh.z) + fmaf(av0, wv.z, bv.z), 0.f);
                        a3 += fmaxf(fmaf(x0.w, sc.w, sh.w) + fmaf(av0, wv.w, bv.w), 0.f);
                    }
                }
            }
        }
        a0 += __shfl_xor(a0, 32);
        a1 += __shfl_xor(a1, 32);
        a2 += __shfl_xor(a2, 32);
        a3 += __shfl_xor(a3, 32);
        if (half == 0) {
            if (n < NN) {
                float4 x = *(const float4*)(X + (size_t)n * INC + c4);
                a0 += fmaf(x.x, sc.x, sh.x);
                a1 += fmaf(x.y, sc.y, sh.y);
                a2 += fmaf(x.z, sc.z, sh.z);
                a3 += fmaf(x.w, sc.w, sh.w);
            }
            *(float4*)&u_s[r][c4] = make_float4(a0, a1, a2, a3);
        }
    }
    __syncthreads();
    // GEMM: 32x64 outputs, 512 threads -> 4 outputs each
    const int cc = t & 15;
    const int rg = t >> 4;                 // row 0..31
    float acc0 = bvec[cc], acc1 = bvec[cc + 16], acc2 = bvec[cc + 32], acc3 = bvec[cc + 48];
    #pragma unroll 4
    for (int k = 0; k < INC; k += 4) {
        float4 w0 = *(const float4*)&w_s[cc][k];
        float4 w1 = *(const float4*)&w_s[cc + 16][k];
        float4 w2 = *(const float4*)&w_s[cc + 32][k];
        float4 w3 = *(const float4*)&w_s[cc + 48][k];
        float4 u = *(const float4*)&u_s[rg][k];
        acc0 = fmaf(u.x, w0.x, fmaf(u.y, w0.y, fmaf(u.z, w0.z, fmaf(u.w, w0.w, acc0))));
        acc1 = fmaf(u.x, w1.x, fmaf(u.y, w1.y, fmaf(u.z, w1.z, fmaf(u.w, w1.w, acc1))));
        acc2 = fmaf(u.x, w2.x, fmaf(u.y, w2.y, fmaf(u.z, w2.z, fmaf(u.w, w2.w, acc2))));
        acc3 = fmaf(u.x, w3.x, fmaf(u.y, w3.y, fmaf(u.z, w3.z, fmaf(u.w, w3.w, acc3))));
    }
    int rr = row0 + rg;
    float t0 = tanhf(acc0), t1v = tanhf(acc1), t2v = tanhf(acc2), t3v = tanhf(acc3);
    if (rr < NN) {
        float* op = t1_ws + (size_t)rr * DIM;
        op[cc] = t0; op[cc + 16] = t1v; op[cc + 32] = t2v; op[cc + 48] = t3v;
    }
    // fused per-channel stats (reuse w_s as [32 rows][64 cols] x2)
    __syncthreads();
    float* red_s = (float*)w_s;
    float* red_q = red_s + 2048;
    bool ok = (rr < NN);
    red_s[rg * 64 + cc]      = ok ? t0 : 0.f;
    red_s[rg * 64 + cc + 16] = ok ? t1v : 0.f;
    red_s[rg * 64 + cc + 32] = ok ? t2v : 0.f;
    red_s[rg * 64 + cc + 48] = ok ? t3v : 0.f;
    red_q[rg * 64 + cc]      = ok ? t0 * t0 : 0.f;
    red_q[rg * 64 + cc + 16] = ok ? t1v * t1v : 0.f;
    red_q[rg * 64 + cc + 32] = ok ? t2v * t2v : 0.f;
    red_q[rg * 64 + cc + 48] = ok ? t3v * t3v : 0.f;
    __syncthreads();
    if (t < 64) {
        float s = 0.f, q = 0.f;
        #pragma unroll
        for (int i = 0; i < 32; i++) { s += red_s[i * 64 + t]; q += red_q[i * 64 + t]; }
        atomicAdd(&dsum0[t], (double)s);
        atomicAdd(&dsq0[t], (double)q);
    }
}

// ---------------- fused layer 1: BN(t1) on the fly + h1 write + gather-agg + GEMM + tanh + stats ----------------
// 64 nodes per 512-thread block. reads packed t1_ws; h1 -> out[:,0:64]; t2 -> out[:,64:128]
__global__ __launch_bounds__(512) void gine1_kernel(const float* __restrict__ t1_ws,
        const int* __restrict__ offs, const int2* __restrict__ src_ea,
        const double* __restrict__ dsum, const double* __restrict__ dsq,
        const float* __restrict__ g, const float* __restrict__ b,
        const float* __restrict__ We, const float* __restrict__ be,
        const float* __restrict__ W, const float* __restrict__ bvec,
        float* __restrict__ out, double* __restrict__ dsum1, double* __restrict__ dsq1) {
    __shared__ __align__(16) float u_s[64][DIM + 4];   // 17.4 KB
    __shared__ __align__(16) float w_s[DIM][DIM + 4];  // 17.4 KB (reused for stats reduce)
    __shared__ float sc_s[DIM], sh_s[DIM];
    const int t = threadIdx.x;
    const int row0 = blockIdx.x * 64;
    bn_fold(t, DIM, dsum, dsq, g, b, sc_s, sh_s);
    for (int i = t; i < DIM * DIM; i += 512) {
        int k = i >> 6, c = i & 63;
        w_s[c][k] = W[i];
    }
    __syncthreads();
    const int wid = t >> 6, l = t & 63;
    const int half = l >> 5;
    const int c2 = (l & 31) * 2;
    float2 wv = *(const float2*)(We + c2);
    float2 bv = *(const float2*)(be + c2);
    float2 sc2 = *(const float2*)(sc_s + c2);
    float2 sh2 = *(const float2*)(sh_s + c2);
    for (int nn = 0; nn < 8; ++nn) {
        int r = wid * 8 + nn;
        int n = row0 + r;
        float a0 = 0.f, a1 = 0.f;
        if (n < NN) {
            int beg = offs[n], end = offs[n + 1];
            for (int base = beg; base < end; base += 64) {
                int j = base + l;
                int2 p = (j < end) ? src_ea[j] : make_int2(0, 0);
                float avf = __int_as_float(p.y);
                int cnt = min(64, end - base);
                int tt = 0;
                for (; tt + 8 <= cnt; tt += 8) {
                    int e0 = tt + half, e1 = tt + 2 + half, e2 = tt + 4 + half, e3 = tt + 6 + half;
                    int s0 = __shfl(p.x, e0), s1 = __shfl(p.x, e1), s2 = __shfl(p.x, e2), s3 = __shfl(p.x, e3);
                    float av0 = __shfl(avf, e0), av1 = __shfl(avf, e1), av2 = __shfl(avf, e2), av3 = __shfl(avf, e3);
                    float2 h0 = *(const float2*)(t1_ws + (size_t)s0 * DIM + c2);
                    float2 hA = *(const float2*)(t1_ws + (size_t)s1 * DIM + c2);
                    float2 hB = *(const float2*)(t1_ws + (size_t)s2 * DIM + c2);
                    float2 hC = *(const float2*)(t1_ws + (size_t)s3 * DIM + c2);
                    a0 += fmaxf(fmaf(h0.x, sc2.x, sh2.x) + fmaf(av0, wv.x, bv.x), 0.f);
                    a1 += fmaxf(fmaf(h0.y, sc2.y, sh2.y) + fmaf(av0, wv.y, bv.y), 0.f);
                    a0 += fmaxf(fmaf(hA.x, sc2.x, sh2.x) + fmaf(av1, wv.x, bv.x), 0.f);
                    a1 += fmaxf(fmaf(hA.y, sc2.y, sh2.y) + fmaf(av1, wv.y, bv.y), 0.f);
                    a0 += fmaxf(fmaf(hB.x, sc2.x, sh2.x) + fmaf(av2, wv.x, bv.x), 0.f);
                    a1 += fmaxf(fmaf(hB.y, sc2.y, sh2.y) + fmaf(av2, wv.y, bv.y), 0.f);
                    a0 += fmaxf(fmaf(hC.x, sc2.x, sh2.x) + fmaf(av3, wv.x, bv.x), 0.f);
                    a1 += fmaxf(fmaf(hC.y, sc2.y, sh2.y) + fmaf(av3, wv.y, bv.y), 0.f);
                }
                for (; tt < cnt; tt += 2) {
                    int e0 = tt + half;
                    int es = min(e0, cnt - 1);
                    int s0 = __shfl(p.x, es);
                    float av0 = __shfl(avf, es);
                    if (e0 < cnt) {
                        float2 h0 = *(const float2*)(t1_ws + (size_t)s0 * DIM + c2);
                        a0 += fmaxf(fmaf(h0.x, sc2.x, sh2.x) + fmaf(av0, wv.x, bv.x), 0.f);
                        a1 += fmaxf(fmaf(h0.y, sc2.y, sh2.y) + fmaf(av0, wv.y, bv.y), 0.f);
                    }
                }
            }
        }
        a0 += __shfl_xor(a0, 32);
        a1 += __shfl_xor(a1, 32);
        if (half == 0) {
            if (n < NN) {
                float2 h = *(const float2*)(t1_ws + (size_t)n * DIM + c2);
                float h1x = fmaf(h.x, sc2.x, sh2.x);
                float h1y = fmaf(h.y, sc2.y, sh2.y);
                *(float2*)(out + (size_t)n * 192 + c2) = make_float2(h1x, h1y);   // h1
                a0 += h1x;
                a1 += h1y;
            }
            *(float2*)&u_s[r][c2] = make_float2(a0, a1);
        }
    }
    __syncthreads();
    // GEMM: 64x64 outputs, 512 threads -> 8 outputs each (2 rows x 4 cols)
    const int cc = t & 15;
    const int r0 = (t >> 4) * 2;
    float acc[2][4];
    #pragma unroll
    for (int j = 0; j < 4; j++) {
        float bj = bvec[cc + 16 * j];
        acc[0][j] = bj; acc[1][j] = bj;
    }
    #pragma unroll 4
    for (int k = 0; k < DIM; k += 4) {
        float4 w0 = *(const float4*)&w_s[cc][k];
        float4 w1 = *(const float4*)&w_s[cc + 16][k];
        float4 w2 = *(const float4*)&w_s[cc + 32][k];
        float4 w3 = *(const float4*)&w_s[cc + 48][k];
        #pragma unroll
        for (int i = 0; i < 2; i++) {
            float4 u = *(const float4*)&u_s[r0 + i][k];
            acc[i][0] = fmaf(u.x, w0.x, fmaf(u.y, w0.y, fmaf(u.z, w0.z, fmaf(u.w, w0.w, acc[i][0]))));
            acc[i][1] = fmaf(u.x, w1.x, fmaf(u.y, w1.y, fmaf(u.z, w1.z, fmaf(u.w, w1.w, acc[i][1]))));
            acc[i][2] = fmaf(u.x, w2.x, fmaf(u.y, w2.y, fmaf(u.z, w2.z, fmaf(u.w, w2.w, acc[i][2]))));
            acc[i][3] = fmaf(u.x, w3.x, fmaf(u.y, w3.y, fmaf(u.z, w3.z, fmaf(u.w, w3.w, acc[i][3]))));
        }
    }
    float tv[2][4];
    #pragma unroll
    for (int i = 0; i < 2; i++) {
        int rr = row0 + r0 + i;
        #pragma unroll
        for (int j = 0; j < 4; j++) tv[i][j] = tanhf(acc[i][j]);
        if (rr < NN) {
            float* op = out + (size_t)rr * 192 + 64;
            #pragma unroll
            for (int j = 0; j < 4; j++) op[cc + 16 * j] = tv[i][j];
        }
    }
    // fused per-channel stats of t2 (reuse w_s as [32 rowgrps][64 cols] x2)
    __syncthreads();
    float* red_s = (float*)w_s;
    float* red_q = red_s + 2048;
    const int rgp = t >> 4;
    bool ok0 = (row0 + r0 < NN), ok1 = (row0 + r0 + 1 < NN);
    #pragma unroll
    for (int j = 0; j < 4; j++) {
        float v0 = ok0 ? tv[0][j] : 0.f;
        float v1 = ok1 ? tv[1][j] : 0.f;
        red_s[rgp * 64 + cc + 16 * j] = v0 + v1;
        red_q[rgp * 64 + cc + 16 * j] = v0 * v0 + v1 * v1;
    }
    __syncthreads();
    if (t < 64) {
        float s = 0.f, q = 0.f;
        #pragma unroll
        for (int i = 0; i < 32; i++) { s += red_s[i * 64 + t]; q += red_q[i * 64 + t]; }
        atomicAdd(&dsum1[t], (double)s);
        atomicAdd(&dsq1[t], (double)q);
    }
}

// ---------------- fused: finalize1 + h2 = BN(t2) in place + h3 = tanh(h2 @ Wfc) ----------------
__global__ __launch_bounds__(256) void fc_kernel(float* __restrict__ io,
        const double* __restrict__ dsum, const double* __restrict__ dsq,
        const float* __restrict__ g, const float* __restrict__ b,
        const float* __restrict__ W) {
    __shared__ __align__(16) float u_s[64][DIM + 4];
    __shared__ __align__(16) float w_s[DIM][DIM + 4];
    __shared__ float sc_s[DIM], sh_s[DIM];
    const int t = threadIdx.x;
    const int row0 = blockIdx.x * 64;
    bn_fold(t, DIM, dsum, dsq, g, b, sc_s, sh_s);
    __syncthreads();
    for (int i = t; i < DIM * DIM; i += 256) {
        int k = i >> 6, c = i & 63;
        w_s[c][k] = W[i];
    }
    for (int i = t; i < 64 * DIM; i += 256) {
        int r = i >> 6, k = i & 63;
        int rr = row0 + r;
        float v = 0.f;
        if (rr < NN) {
            size_t idx = (size_t)rr * 192 + 64 + k;
            v = fmaf(io[idx], sc_s[k], sh_s[k]);
            io[idx] = v;                       // h2
        }
        u_s[r][k] = v;
    }
    __syncthreads();
    const int cc = t & 15;
    const int r0 = (t >> 4) << 2;
    float acc[4][4];
    #pragma unroll
    for (int j = 0; j < 4; j++) { acc[0][j] = 0.f; acc[1][j] = 0.f; acc[2][j] = 0.f; acc[3][j] = 0.f; }
    #pragma unroll 4
    for (int k = 0; k < DIM; k += 4) {
        float4 w0 = *(const float4*)&w_s[cc][k];
        float4 w1 = *(const float4*)&w_s[cc + 16][k];
        float4 w2 = *(const float4*)&w_s[cc + 32][k];
        float4 w3 = *(const float4*)&w_s[cc + 48][k];
        #pragma unroll
        for (int i = 0; i < 4; i++) {
            float4 u = *(const float4*)&u_s[r0 + i][k];
            acc[i][0] = fmaf(u.x, w0.x, fmaf(u.y, w0.y, fmaf(u.z, w0.z, fmaf(u.w, w0.w, acc[i][0]))));
            acc[i][1] = fmaf(u.x, w1.x, fmaf(u.y, w1.y, fmaf(u.z, w1.z, fmaf(u.w, w1.w, acc[i][1]))));
            acc[i][2] = fmaf(u.x, w2.x, fmaf(u.y, w2.y, fmaf(u.z, w2.z, fmaf(u.w, w2.w, acc[i][2]))));
            acc[i][3] = fmaf(u.x, w3.x, fmaf(u.y, w3.y, fmaf(u.z, w3.z, fmaf(u.w, w3.w, acc[i][3]))));
        }
    }
    #pragma unroll
    for (int i = 0; i < 4; i++) {
        int rr = row0 + r0 + i;
        if (rr < NN) {
            #pragma unroll
            for (int j = 0; j < 4; j++)
                io[(size_t)rr * 192 + 128 + cc + 16 * j] = tanhf(acc[i][j]);
        }
    }
}

extern "C" void kernel_launch(void* const* d_in, const int* in_sizes, int n_in,
                              void* d_out, int out_size, void* d_ws, size_t ws_size,
                              hipStream_t stream) {
    const float* X      = (const float*)d_in[0];
    const int*   ei     = (const int*)  d_in[1];
    const float* ea     = (const float*)d_in[2];
    const float* bng    = (const float*)d_in[3];
    const float* bnb    = (const float*)d_in[4];
    const float* We0    = (const float*)d_in[5];
    const float* be0    = (const float*)d_in[6];
    const float* W0     = (const float*)d_in[7];
    const float* b0     = (const float*)d_in[8];
    const float* bn0g   = (const float*)d_in[9];
    const float* bn0b   = (const float*)d_in[10];
    const float* We1    = (const float*)d_in[11];
    const float* be1    = (const float*)d_in[12];
    const float* W1     = (const float*)d_in[13];
    const float* b1     = (const float*)d_in[14];
    const float* bn1g   = (const float*)d_in[15];
    const float* bn1b   = (const float*)d_in[16];
    const float* Wfc    = (const float*)d_in[17];

    const int* src = ei;
    const int* dst = ei + NE;
    float* out = (float*)d_out;

    // ---- workspace layout (~58 MB) ----
    int2*  src_ea   = (int2*)d_ws;                      // NE
    int2*  stage_se = src_ea + NE;                      // NE
    int*   stage_d  = (int*)(stage_se + NE);            // NE
    float* t1_ws    = (float*)(stage_d + NE);           // NN*DIM
    int*   counts   = (int*)(t1_ws + (size_t)NN * DIM); // NN
    int*   offs     = counts + NN;                      // NN+1
    int*   bcur     = offs + NN + 1;                    // NBK
    int*   bsums    = bcur + NBK;                       // 128
    double* dstats = (double*)(((uintptr_t)(bsums + 128) + 15) & ~(uintptr_t)15);
    double* dsum_in = dstats;        double* dsq_in = dstats + 128;
    double* dsum0   = dstats + 256;  double* dsq0   = dstats + 320;
    double* dsum1   = dstats + 384;  double* dsq1   = dstats + 448;

    hipMemsetAsync(counts, 0, NN * sizeof(int), stream);
    hipMemsetAsync(dstats, 0, 512 * sizeof(double), stream);

    // fused input-BN stats + dst histogram
    stats_hist_kernel<<<SB + (NE + 255) / 256, 256, 0, stream>>>(X, dst, counts, dsum_in, dsq_in);

    // CSR build (shared by both layers)
    const int NB = (NN + 1023) / 1024;   // 98
    scan1_kernel<<<NB, 1024, 0, stream>>>(counts, offs, bsums);
    scan2_kernel<<<1, 128, 0, stream>>>(bsums, NB);
    scan3_kernel<<<(NN + 255) / 256, 256, 0, stream>>>(offs, bsums, bcur);
    scatterA_kernel<<<NE / 256, 256, 0, stream>>>(src, dst, ea, bcur, stage_se, stage_d);
    scatterB_kernel<<<NBK, 256, 0, stream>>>(offs, stage_se, stage_d, src_ea);

    // layer 0 (fused finalize_in + agg + GEMM + stats0)
    gine0_kernel<<<(NN + 31) / 32, 512, 0, stream>>>(X, offs, src_ea, dsum_in, dsq_in, bng, bnb,
                                                     We0, be0, W0, b0, t1_ws, dsum0, dsq0);

    // layer 1 (fused finalize0 + BN-on-fly + h1 write + agg + GEMM + stats1)
    gine1_kernel<<<(NN + 63) / 64, 512, 0, stream>>>(t1_ws, offs, src_ea, dsum0, dsq0, bn0g, bn0b,
                                                     We1, be1, W1, b1, out, dsum1, dsq1);

    // h2 (in place) + h3 (fused finalize1)
    fc_kernel<<<(NN + 63) / 64, 256, 0, stream>>>(out, dsum1, dsq1, bn1g, bn1b, Wfc);
}

// Round 6
// 600.516 us; speedup vs baseline: 1.4596x; 1.4596x over previous
//
#include <hip/hip_runtime.h>
#include <math.h>
#include <stdint.h>

#define NN 100000
#define NE 1600000
#define INC 128
#define DIM 64
#define EPS 1e-5f
#define SB 512   // stats blocks inside fused stats+hist kernel

// fused: blocks [0,SB) do X stats (C=128) in f64; blocks [SB,...) do dst histogram
__global__ __launch_bounds__(256) void stats_hist_kernel(const float* __restrict__ X,
        const int* __restrict__ dst, int* __restrict__ counts,
        double* __restrict__ sum_out, double* __restrict__ sq_out) {
    __shared__ double ls[256], lq[256];
    if (blockIdx.x < SB) {
        int c  = threadIdx.x & 127;
        int rl = threadIdx.x >> 7;           // 2 rows per block step
        int row = blockIdx.x * 2 + rl;
        const int rstride = SB * 2;
        double s = 0.0, q = 0.0;
        for (int r = row; r < NN; r += rstride) {
            double v = (double)X[(size_t)r * INC + c];
            s += v; q += v * v;
        }
        ls[threadIdx.x] = s; lq[threadIdx.x] = q;
        __syncthreads();
        if (rl == 0) {
            s += ls[128 + c]; q += lq[128 + c];
            atomicAdd(&sum_out[c], s);
            atomicAdd(&sq_out[c], q);
        }
    } else {
        int e = (blockIdx.x - SB) * 256 + threadIdx.x;
        if (e < NE) atomicAdd(&counts[dst[e]], 1);
    }
}

// BN scale/shift from f64 stats (device helper, computed redundantly per block)
__device__ inline void bn_fold(int t, int C, const double* dsum, const double* dsq,
                               const float* g, const float* b, float* sc_s, float* sh_s) {
    if (t < C) {
        double m = dsum[t] / (double)NN;
        double v = dsq[t] / (double)NN - m * m;
        double sc = (double)g[t] / sqrt(v + (double)EPS);
        sc_s[t] = (float)sc;
        sh_s[t] = (float)((double)b[t] - m * sc);
    }
}

// ---------------- CSR build: scan ----------------
__global__ __launch_bounds__(1024) void scan1_kernel(const int* __restrict__ counts,
                                                     int* __restrict__ offs, int* __restrict__ bsums) {
    __shared__ int tmp[2][1024];
    int t = threadIdx.x;
    int g = blockIdx.x * 1024 + t;
    int v = (g < NN) ? counts[g] : 0;
    tmp[0][t] = v;
    __syncthreads();
    int pin = 0;
    for (int d = 1; d < 1024; d <<= 1) {
        int x = tmp[pin][t] + ((t >= d) ? tmp[pin][t - d] : 0);
        tmp[pin ^ 1][t] = x;
        pin ^= 1;
        __syncthreads();
    }
    int incl = tmp[pin][t];
    if (g < NN) offs[g] = incl - v;
    if (t == 1023) bsums[blockIdx.x] = incl;
}

__global__ __launch_bounds__(128) void scan2_kernel(int* __restrict__ bsums, int nb) {
    __shared__ int tmp[2][128];
    int t = threadIdx.x;
    int v = (t < nb) ? bsums[t] : 0;
    tmp[0][t] = v;
    __syncthreads();
    int pin = 0;
    for (int d = 1; d < 128; d <<= 1) {
        int x = tmp[pin][t] + ((t >= d) ? tmp[pin][t - d] : 0);
        tmp[pin ^ 1][t] = x;
        pin ^= 1;
        __syncthreads();
    }
    if (t < nb) bsums[t] = tmp[pin][t] - v;
}

// final offsets + per-node scatter cursors
__global__ __launch_bounds__(256) void scan3_kernel(int* __restrict__ offs, const int* __restrict__ bsums,
                                                    int* __restrict__ cursor) {
    int g = blockIdx.x * 256 + threadIdx.x;
    if (g < NN) {
        int o = offs[g] + bsums[g >> 10];
        offs[g] = o;
        cursor[g] = o;
    }
    if (g == 0) offs[NN] = NE;
}

// direct scatter: one 8B store per edge, 100K cursors (low contention, ~16 edges/node)
__global__ __launch_bounds__(256) void scatter_kernel(const int* __restrict__ src, const int* __restrict__ dst,
                                                      const float* __restrict__ ea, int* __restrict__ cursor,
                                                      int2* __restrict__ src_ea) {
    int e = blockIdx.x * 256 + threadIdx.x;
    if (e >= NE) return;
    int d = dst[e];
    int pos = atomicAdd(&cursor[d], 1);
    src_ea[pos] = make_int2(src[e], __float_as_int(ea[e]));
}

// ---------------- fused layer 0: BN-fold + gather-agg (half-wave) + GEMM + tanh + stats ----------------
// 32 nodes per 512-thread block. t1 -> t1_ws [NN][64] packed; per-channel stats -> dsum0/dsq0
__global__ __launch_bounds__(512) void gine0_kernel(const float* __restrict__ X,
        const int* __restrict__ offs, const int2* __restrict__ src_ea,
        const double* __restrict__ dsum, const double* __restrict__ dsq,
        const float* __restrict__ g, const float* __restrict__ b,
        const float* __restrict__ We, const float* __restrict__ be,
        const float* __restrict__ W, const float* __restrict__ bvec,
        float* __restrict__ t1_ws, double* __restrict__ dsum0, double* __restrict__ dsq0) {
    __shared__ __align__(16) float u_s[32][INC + 4];   // 16.9 KB
    __shared__ __align__(16) float w_s[DIM][INC + 4];  // 33.8 KB (reused for stats reduce)
    __shared__ float sc_s[INC], sh_s[INC];
    const int t = threadIdx.x;
    const int row0 = blockIdx.x * 32;
    bn_fold(t, INC, dsum, dsq, g, b, sc_s, sh_s);
    for (int i = t; i < INC * DIM; i += 512) {
        int k = i >> 6, c = i & 63;
        w_s[c][k] = W[i];
    }
    __syncthreads();
    // gather: 8 waves x 4 nodes; within a wave, halves process 2 edges at a time
    const int wid = t >> 6, l = t & 63;
    const int half = l >> 5;
    const int c4 = (l & 31) * 4;
    float4 sc = *(const float4*)(sc_s + c4);
    float4 sh = *(const float4*)(sh_s + c4);
    float4 wv = *(const float4*)(We + c4);
    float4 bv = *(const float4*)(be + c4);
    for (int nn = 0; nn < 4; ++nn) {
        int r = wid * 4 + nn;
        int n = row0 + r;
        float a0 = 0.f, a1 = 0.f, a2 = 0.f, a3 = 0.f;
        if (n < NN) {
            int beg = offs[n], end = offs[n + 1];
            for (int base = beg; base < end; base += 64) {
                int j = base + l;
                int2 p = (j < end) ? src_ea[j] : make_int2(0, 0);
                float avf = __int_as_float(p.y);
                int cnt = min(64, end - base);
                int tt = 0;
                for (; tt + 4 <= cnt; tt += 4) {
                    int e0 = tt + half, e1 = tt + 2 + half;
                    int s0 = __shfl(p.x, e0), s1 = __shfl(p.x, e1);
                    float av0 = __shfl(avf, e0), av1 = __shfl(avf, e1);
                    float4 x0 = *(const float4*)(X + (size_t)s0 * INC + c4);
                    float4 x1 = *(const float4*)(X + (size_t)s1 * INC + c4);
                    a0 += fmaxf(fmaf(x0.x, sc.x, sh.x) + fmaf(av0, wv.x, bv.x), 0.f);
                    a1 += fmaxf(fmaf(x0.y, sc.y, sh.y) + fmaf(av0, wv.y, bv.y), 0.f);
                    a2 += fmaxf(fmaf(x0.z, sc.z, sh.z) + fmaf(av0, wv.z, bv.z), 0.f);
                    a3 += fmaxf(fmaf(x0.w, sc.w, sh.w) + fmaf(av0, wv.w, bv.w), 0.f);
                    a0 += fmaxf(fmaf(x1.x, sc.x, sh.x) + fmaf(av1, wv.x, bv.x), 0.f);
                    a1 += fmaxf(fmaf(x1.y, sc.y, sh.y) + fmaf(av1, wv.y, bv.y), 0.f);
                    a2 += fmaxf(fmaf(x1.z, sc.z, sh.z) + fmaf(av1, wv.z, bv.z), 0.f);
                    a3 += fmaxf(fmaf(x1.w, sc.w, sh.w) + fmaf(av1, wv.w, bv.w), 0.f);
                }
                for (; tt < cnt; tt += 2) {
                    int e0 = tt + half;
                    int es = min(e0, cnt - 1);
                    int s0 = __shfl(p.x, es);
                    float av0 = __shfl(avf, es);
                    if (e0 < cnt) {
                        float4 x0 = *(const float4*)(X + (size_t)s0 * INC + c4);
                        a0 += fmaxf(fmaf(x0.x, sc.x, sh.x) + fmaf(av0, wv.x, bv.x), 0.f);
                        a1 += fmaxf(fmaf(x0.y, sc.y, sh.y) + fmaf(av0, wv.y, bv.y), 0.f);
                        a2 += fmaxf(fmaf(x0.z, sc.z, sh.z) + fmaf(av0, wv.z, bv.z), 0.f);
                        a3 += fmaxf(fmaf(x0.w, sc.w, sh.w) + fmaf(av0, wv.w, bv.w), 0.f);
                    }
                }
            }
        }
        a0 += __shfl_xor(a0, 32);
        a1 += __shfl_xor(a1, 32);
        a2 += __shfl_xor(a2, 32);
        a3 += __shfl_xor(a3, 32);
        if (half == 0) {
            if (n < NN) {
                float4 x = *(const float4*)(X + (size_t)n * INC + c4);
                a0 += fmaf(x.x, sc.x, sh.x);
                a1 += fmaf(x.y, sc.y, sh.y);
                a2 += fmaf(x.z, sc.z, sh.z);
                a3 += fmaf(x.w, sc.w, sh.w);
            }
            *(float4*)&u_s[r][c4] = make_float4(a0, a1, a2, a3);
        }
    }
    __syncthreads();
    // GEMM: 32x64 outputs, 512 threads -> 4 outputs each
    const int cc = t & 15;
    const int rg = t >> 4;                 // row 0..31
    float acc0 = bvec[cc], acc1 = bvec[cc + 16], acc2 = bvec[cc + 32], acc3 = bvec[cc + 48];
    #pragma unroll 4
    for (int k = 0; k < INC; k += 4) {
        float4 w0 = *(const float4*)&w_s[cc][k];
        float4 w1 = *(const float4*)&w_s[cc + 16][k];
        float4 w2 = *(const float4*)&w_s[cc + 32][k];
        float4 w3 = *(const float4*)&w_s[cc + 48][k];
        float4 u = *(const float4*)&u_s[rg][k];
        acc0 = fmaf(u.x, w0.x, fmaf(u.y, w0.y, fmaf(u.z, w0.z, fmaf(u.w, w0.w, acc0))));
        acc1 = fmaf(u.x, w1.x, fmaf(u.y, w1.y, fmaf(u.z, w1.z, fmaf(u.w, w1.w, acc1))));
        acc2 = fmaf(u.x, w2.x, fmaf(u.y, w2.y, fmaf(u.z, w2.z, fmaf(u.w, w2.w, acc2))));
        acc3 = fmaf(u.x, w3.x, fmaf(u.y, w3.y, fmaf(u.z, w3.z, fmaf(u.w, w3.w, acc3))));
    }
    int rr = row0 + rg;
    float t0 = tanhf(acc0), t1v = tanhf(acc1), t2v = tanhf(acc2), t3v = tanhf(acc3);
    if (rr < NN) {
        float* op = t1_ws + (size_t)rr * DIM;
        op[cc] = t0; op[cc + 16] = t1v; op[cc + 32] = t2v; op[cc + 48] = t3v;
    }
    // fused per-channel stats (reuse w_s as [32 rows][64 cols] x2)
    __syncthreads();
    float* red_s = (float*)w_s;
    float* red_q = red_s + 2048;
    bool ok = (rr < NN);
    red_s[rg * 64 + cc]      = ok ? t0 : 0.f;
    red_s[rg * 64 + cc + 16] = ok ? t1v : 0.f;
    red_s[rg * 64 + cc + 32] = ok ? t2v : 0.f;
    red_s[rg * 64 + cc + 48] = ok ? t3v : 0.f;
    red_q[rg * 64 + cc]      = ok ? t0 * t0 : 0.f;
    red_q[rg * 64 + cc + 16] = ok ? t1v * t1v : 0.f;
    red_q[rg * 64 + cc + 32] = ok ? t2v * t2v : 0.f;
    red_q[rg * 64 + cc + 48] = ok ? t3v * t3v : 0.f;
    __syncthreads();
    if (t < 64) {
        float s = 0.f, q = 0.f;
        #pragma unroll
        for (int i = 0; i < 32; i++) { s += red_s[i * 64 + t]; q += red_q[i * 64 + t]; }
        atomicAdd(&dsum0[t], (double)s);
        atomicAdd(&dsq0[t], (double)q);
    }
}

// ---------------- fused layer 1: BN(t1) on the fly + h1 write + gather-agg + GEMM + tanh + stats ----------------
// 64 nodes per 512-thread block. reads packed t1_ws; h1 -> out[:,0:64]; t2 -> out[:,64:128]
__global__ __launch_bounds__(512) void gine1_kernel(const float* __restrict__ t1_ws,
        const int* __restrict__ offs, const int2* __restrict__ src_ea,
        const double* __restrict__ dsum, const double* __restrict__ dsq,
        const float* __restrict__ g, const float* __restrict__ b,
        const float* __restrict__ We, const float* __restrict__ be,
        const float* __restrict__ W, const float* __restrict__ bvec,
        float* __restrict__ out, double* __restrict__ dsum1, double* __restrict__ dsq1) {
    __shared__ __align__(16) float u_s[64][DIM + 4];   // 17.4 KB
    __shared__ __align__(16) float w_s[DIM][DIM + 4];  // 17.4 KB (reused for stats reduce)
    __shared__ float sc_s[DIM], sh_s[DIM];
    const int t = threadIdx.x;
    const int row0 = blockIdx.x * 64;
    bn_fold(t, DIM, dsum, dsq, g, b, sc_s, sh_s);
    for (int i = t; i < DIM * DIM; i += 512) {
        int k = i >> 6, c = i & 63;
        w_s[c][k] = W[i];
    }
    __syncthreads();
    const int wid = t >> 6, l = t & 63;
    const int half = l >> 5;
    const int c2 = (l & 31) * 2;
    float2 wv = *(const float2*)(We + c2);
    float2 bv = *(const float2*)(be + c2);
    float2 sc2 = *(const float2*)(sc_s + c2);
    float2 sh2 = *(const float2*)(sh_s + c2);
    for (int nn = 0; nn < 8; ++nn) {
        int r = wid * 8 + nn;
        int n = row0 + r;
        float a0 = 0.f, a1 = 0.f;
        if (n < NN) {
            int beg = offs[n], end = offs[n + 1];
            for (int base = beg; base < end; base += 64) {
                int j = base + l;
                int2 p = (j < end) ? src_ea[j] : make_int2(0, 0);
                float avf = __int_as_float(p.y);
                int cnt = min(64, end - base);
                int tt = 0;
                for (; tt + 8 <= cnt; tt += 8) {
                    int e0 = tt + half, e1 = tt + 2 + half, e2 = tt + 4 + half, e3 = tt + 6 + half;
                    int s0 = __shfl(p.x, e0), s1 = __shfl(p.x, e1), s2 = __shfl(p.x, e2), s3 = __shfl(p.x, e3);
                    float av0 = __shfl(avf, e0), av1 = __shfl(avf, e1), av2 = __shfl(avf, e2), av3 = __shfl(avf, e3);
                    float2 h0 = *(const float2*)(t1_ws + (size_t)s0 * DIM + c2);
                    float2 hA = *(const float2*)(t1_ws + (size_t)s1 * DIM + c2);
                    float2 hB = *(const float2*)(t1_ws + (size_t)s2 * DIM + c2);
                    float2 hC = *(const float2*)(t1_ws + (size_t)s3 * DIM + c2);
                    a0 += fmaxf(fmaf(h0.x, sc2.x, sh2.x) + fmaf(av0, wv.x, bv.x), 0.f);
                    a1 += fmaxf(fmaf(h0.y, sc2.y, sh2.y) + fmaf(av0, wv.y, bv.y), 0.f);
                    a0 += fmaxf(fmaf(hA.x, sc2.x, sh2.x) + fmaf(av1, wv.x, bv.x), 0.f);
                    a1 += fmaxf(fmaf(hA.y, sc2.y, sh2.y) + fmaf(av1, wv.y, bv.y), 0.f);
                    a0 += fmaxf(fmaf(hB.x, sc2.x, sh2.x) + fmaf(av2, wv.x, bv.x), 0.f);
                    a1 += fmaxf(fmaf(hB.y, sc2.y, sh2.y) + fmaf(av2, wv.y, bv.y), 0.f);
                    a0 += fmaxf(fmaf(hC.x, sc2.x, sh2.x) + fmaf(av3, wv.x, bv.x), 0.f);
                    a1 += fmaxf(fmaf(hC.y, sc2.y, sh2.y) + fmaf(av3, wv.y, bv.y), 0.f);
                }
                for (; tt < cnt; tt += 2) {
                    int e0 = tt + half;
                    int es = min(e0, cnt - 1);
                    int s0 = __shfl(p.x, es);
                    float av0 = __shfl(avf, es);
                    if (e0 < cnt) {
                        float2 h0 = *(const float2*)(t1_ws + (size_t)s0 * DIM + c2);
                        a0 += fmaxf(fmaf(h0.x, sc2.x, sh2.x) + fmaf(av0, wv.x, bv.x), 0.f);
                        a1 += fmaxf(fmaf(h0.y, sc2.y, sh2.y) + fmaf(av0, wv.y, bv.y), 0.f);
                    }
                }
            }
        }
        a0 += __shfl_xor(a0, 32);
        a1 += __shfl_xor(a1, 32);
        if (half == 0) {
            if (n < NN) {
                float2 h = *(const float2*)(t1_ws + (size_t)n * DIM + c2);
                float h1x = fmaf(h.x, sc2.x, sh2.x);
                float h1y = fmaf(h.y, sc2.y, sh2.y);
                *(float2*)(out + (size_t)n * 192 + c2) = make_float2(h1x, h1y);   // h1
                a0 += h1x;
                a1 += h1y;
            }
            *(float2*)&u_s[r][c2] = make_float2(a0, a1);
        }
    }
    __syncthreads();
    // GEMM: 64x64 outputs, 512 threads -> 8 outputs each (2 rows x 4 cols)
    const int cc = t & 15;
    const int r0 = (t >> 4) * 2;
    float acc[2][4];
    #pragma unroll
    for (int j = 0; j < 4; j++) {
        float bj = bvec[cc + 16 * j];
        acc[0][j] = bj; acc[1][j] = bj;
    }
    #pragma unroll 4
    for (int k = 0; k < DIM; k += 4) {
        float4 w0 = *(const float4*)&w_s[cc][k];
        float4 w1 = *(const float4*)&w_s[cc + 16][k];
        float4 w2 = *(const float4*)&w_s[cc + 32][k];
        float4 w3 = *(const float4*)&w_s[cc + 48][k];
        #pragma unroll
        for (int i = 0; i < 2; i++) {
            float4 u = *(const float4*)&u_s[r0 + i][k];
            acc[i][0] = fmaf(u.x, w0.x, fmaf(u.y, w0.y, fmaf(u.z, w0.z, fmaf(u.w, w0.w, acc[i][0]))));
            acc[i][1] = fmaf(u.x, w1.x, fmaf(u.y, w1.y, fmaf(u.z, w1.z, fmaf(u.w, w1.w, acc[i][1]))));
            acc[i][2] = fmaf(u.x, w2.x, fmaf(u.y, w2.y, fmaf(u.z, w2.z, fmaf(u.w, w2.w, acc[i][2]))));
            acc[i][3] = fmaf(u.x, w3.x, fmaf(u.y, w3.y, fmaf(u.z, w3.z, fmaf(u.w, w3.w, acc[i][3]))));
        }
    }
    float tv[2][4];
    #pragma unroll
    for (int i = 0; i < 2; i++) {
        int rr = row0 + r0 + i;
        #pragma unroll
        for (int j = 0; j < 4; j++) tv[i][j] = tanhf(acc[i][j]);
        if (rr < NN) {
            float* op = out + (size_t)rr * 192 + 64;
            #pragma unroll
            for (int j = 0; j < 4; j++) op[cc + 16 * j] = tv[i][j];
        }
    }
    // fused per-channel stats of t2 (reuse w_s as [32 rowgrps][64 cols] x2)
    __syncthreads();
    float* red_s = (float*)w_s;
    float* red_q = red_s + 2048;
    const int rgp = t >> 4;
    bool ok0 = (row0 + r0 < NN), ok1 = (row0 + r0 + 1 < NN);
    #pragma unroll
    for (int j = 0; j < 4; j++) {
        float v0 = ok0 ? tv[0][j] : 0.f;
        float v1 = ok1 ? tv[1][j] : 0.f;
        red_s[rgp * 64 + cc + 16 * j] = v0 + v1;
        red_q[rgp * 64 + cc + 16 * j] = v0 * v0 + v1 * v1;
    }
    __syncthreads();
    if (t < 64) {
        float s = 0.f, q = 0.f;
        #pragma unroll
        for (int i = 0; i < 32; i++) { s += red_s[i * 64 + t]; q += red_q[i * 64 + t]; }
        atomicAdd(&dsum1[t], (double)s);
        atomicAdd(&dsq1[t], (double)q);
    }
}

// ---------------- fused: finalize1 + h2 = BN(t2) in place + h3 = tanh(h2 @ Wfc) ----------------
__global__ __launch_bounds__(256) void fc_kernel(float* __restrict__ io,
        const double* __restrict__ dsum, const double* __restrict__ dsq,
        const float* __restrict__ g, const float* __restrict__ b,
        const float* __restrict__ W) {
    __shared__ __align__(16) float u_s[64][DIM + 4];
    __shared__ __align__(16) float w_s[DIM][DIM + 4];
    __shared__ float sc_s[DIM], sh_s[DIM];
    const int t = threadIdx.x;
    const int row0 = blockIdx.x * 64;
    bn_fold(t, DIM, dsum, dsq, g, b, sc_s, sh_s);
    __syncthreads();
    for (int i = t; i < DIM * DIM; i += 256) {
        int k = i >> 6, c = i & 63;
        w_s[c][k] = W[i];
    }
    for (int i = t; i < 64 * DIM; i += 256) {
        int r = i >> 6, k = i & 63;
        int rr = row0 + r;
        float v = 0.f;
        if (rr < NN) {
            size_t idx = (size_t)rr * 192 + 64 + k;
            v = fmaf(io[idx], sc_s[k], sh_s[k]);
            io[idx] = v;                       // h2
        }
        u_s[r][k] = v;
    }
    __syncthreads();
    const int cc = t & 15;
    const int r0 = (t >> 4) << 2;
    float acc[4][4];
    #pragma unroll
    for (int j = 0; j < 4; j++) { acc[0][j] = 0.f; acc[1][j] = 0.f; acc[2][j] = 0.f; acc[3][j] = 0.f; }
    #pragma unroll 4
    for (int k = 0; k < DIM; k += 4) {
        float4 w0 = *(const float4*)&w_s[cc][k];
        float4 w1 = *(const float4*)&w_s[cc + 16][k];
        float4 w2 = *(const float4*)&w_s[cc + 32][k];
        float4 w3 = *(const float4*)&w_s[cc + 48][k];
        #pragma unroll
        for (int i = 0; i < 4; i++) {
            float4 u = *(const float4*)&u_s[r0 + i][k];
            acc[i][0] = fmaf(u.x, w0.x, fmaf(u.y, w0.y, fmaf(u.z, w0.z, fmaf(u.w, w0.w, acc[i][0]))));
            acc[i][1] = fmaf(u.x, w1.x, fmaf(u.y, w1.y, fmaf(u.z, w1.z, fmaf(u.w, w1.w, acc[i][1]))));
            acc[i][2] = fmaf(u.x, w2.x, fmaf(u.y, w2.y, fmaf(u.z, w2.z, fmaf(u.w, w2.w, acc[i][2]))));
            acc[i][3] = fmaf(u.x, w3.x, fmaf(u.y, w3.y, fmaf(u.z, w3.z, fmaf(u.w, w3.w, acc[i][3]))));
        }
    }
    #pragma unroll
    for (int i = 0; i < 4; i++) {
        int rr = row0 + r0 + i;
        if (rr < NN) {
            #pragma unroll
            for (int j = 0; j < 4; j++)
                io[(size_t)rr * 192 + 128 + cc + 16 * j] = tanhf(acc[i][j]);
        }
    }
}

extern "C" void kernel_launch(void* const* d_in, const int* in_sizes, int n_in,
                              void* d_out, int out_size, void* d_ws, size_t ws_size,
                              hipStream_t stream) {
    const float* X      = (const float*)d_in[0];
    const int*   ei     = (const int*)  d_in[1];
    const float* ea     = (const float*)d_in[2];
    const float* bng    = (const float*)d_in[3];
    const float* bnb    = (const float*)d_in[4];
    const float* We0    = (const float*)d_in[5];
    const float* be0    = (const float*)d_in[6];
    const float* W0     = (const float*)d_in[7];
    const float* b0     = (const float*)d_in[8];
    const float* bn0g   = (const float*)d_in[9];
    const float* bn0b   = (const float*)d_in[10];
    const float* We1    = (const float*)d_in[11];
    const float* be1    = (const float*)d_in[12];
    const float* W1     = (const float*)d_in[13];
    const float* b1     = (const float*)d_in[14];
    const float* bn1g   = (const float*)d_in[15];
    const float* bn1b   = (const float*)d_in[16];
    const float* Wfc    = (const float*)d_in[17];

    const int* src = ei;
    const int* dst = ei + NE;
    float* out = (float*)d_out;

    // ---- workspace layout (~39 MB) ----
    int2*  src_ea   = (int2*)d_ws;                      // NE
    float* t1_ws    = (float*)(src_ea + NE);            // NN*DIM
    int*   counts   = (int*)(t1_ws + (size_t)NN * DIM); // NN
    int*   offs     = counts + NN;                      // NN+1
    int*   cursor   = offs + NN + 1;                    // NN
    int*   bsums    = cursor + NN;                      // 128
    double* dstats = (double*)(((uintptr_t)(bsums + 128) + 15) & ~(uintptr_t)15);
    double* dsum_in = dstats;        double* dsq_in = dstats + 128;
    double* dsum0   = dstats + 256;  double* dsq0   = dstats + 320;
    double* dsum1   = dstats + 384;  double* dsq1   = dstats + 448;

    hipMemsetAsync(counts, 0, NN * sizeof(int), stream);
    hipMemsetAsync(dstats, 0, 512 * sizeof(double), stream);

    // fused input-BN stats + dst histogram
    stats_hist_kernel<<<SB + (NE + 255) / 256, 256, 0, stream>>>(X, dst, counts, dsum_in, dsq_in);

    // CSR build (shared by both layers)
    const int NB = (NN + 1023) / 1024;   // 98
    scan1_kernel<<<NB, 1024, 0, stream>>>(counts, offs, bsums);
    scan2_kernel<<<1, 128, 0, stream>>>(bsums, NB);
    scan3_kernel<<<(NN + 255) / 256, 256, 0, stream>>>(offs, bsums, cursor);
    scatter_kernel<<<NE / 256, 256, 0, stream>>>(src, dst, ea, cursor, src_ea);

    // layer 0 (fused finalize_in + agg + GEMM + stats0)
    gine0_kernel<<<(NN + 31) / 32, 512, 0, stream>>>(X, offs, src_ea, dsum_in, dsq_in, bng, bnb,
                                                     We0, be0, W0, b0, t1_ws, dsum0, dsq0);

    // layer 1 (fused finalize0 + BN-on-fly + h1 write + agg + GEMM + stats1)
    gine1_kernel<<<(NN + 63) / 64, 512, 0, stream>>>(t1_ws, offs, src_ea, dsum0, dsq0, bn0g, bn0b,
                                                     We1, be1, W1, b1, out, dsum1, dsq1);

    // h2 (in place) + h3 (fused finalize1)
    fc_kernel<<<(NN + 63) / 64, 256, 0, stream>>>(out, dsum1, dsq1, bn1g, bn1b, Wfc);
}

// Round 7
// 510.871 us; speedup vs baseline: 1.7157x; 1.1755x over previous
//
#include <hip/hip_runtime.h>
#include <math.h>
#include <stdint.h>

#define NN 100000
#define NE 1600000
#define INC 128
#define DIM 64
#define EPS 1e-5f
#define SB 512   // stats blocks inside fused stats+hist kernel
#define NREP 8   // stats accumulator replicas (atomic-contention spreading)

// fused: blocks [0,SB) do X stats (C=128) in f64; blocks [SB,...) do dst histogram
__global__ __launch_bounds__(256) void stats_hist_kernel(const float* __restrict__ X,
        const int* __restrict__ dst, int* __restrict__ counts,
        double* __restrict__ sum_out, double* __restrict__ sq_out) {
    __shared__ double ls[256], lq[256];
    if (blockIdx.x < SB) {
        int c  = threadIdx.x & 127;
        int rl = threadIdx.x >> 7;           // 2 rows per block step
        int row = blockIdx.x * 2 + rl;
        const int rstride = SB * 2;
        double s = 0.0, q = 0.0;
        for (int r = row; r < NN; r += rstride) {
            double v = (double)X[(size_t)r * INC + c];
            s += v; q += v * v;
        }
        ls[threadIdx.x] = s; lq[threadIdx.x] = q;
        __syncthreads();
        if (rl == 0) {
            s += ls[128 + c]; q += lq[128 + c];
            // replicate across NREP copies to cut per-line atomic contention
            int rep = blockIdx.x & (NREP - 1);
            atomicAdd(&sum_out[rep * INC + c], s);
            atomicAdd(&sq_out[rep * INC + c], q);
        }
    } else {
        int e = (blockIdx.x - SB) * 256 + threadIdx.x;
        if (e < NE) atomicAdd(&counts[dst[e]], 1);
    }
}

// BN scale/shift from NREP-replicated f64 stats
template<int C>
__device__ inline void bn_fold_rep(int t, const double* dsum, const double* dsq,
                                   const float* g, const float* b, float* sc_s, float* sh_s) {
    if (t < C) {
        double s = 0.0, q = 0.0;
        #pragma unroll
        for (int r = 0; r < NREP; r++) { s += dsum[r * C + t]; q += dsq[r * C + t]; }
        double m = s / (double)NN;
        double v = q / (double)NN - m * m;
        double sc = (double)g[t] / sqrt(v + (double)EPS);
        sc_s[t] = (float)sc;
        sh_s[t] = (float)((double)b[t] - m * sc);
    }
}

// ---------------- CSR build: scan ----------------
__global__ __launch_bounds__(1024) void scan1_kernel(const int* __restrict__ counts,
                                                     int* __restrict__ offs, int* __restrict__ bsums) {
    __shared__ int tmp[2][1024];
    int t = threadIdx.x;
    int g = blockIdx.x * 1024 + t;
    int v = (g < NN) ? counts[g] : 0;
    tmp[0][t] = v;
    __syncthreads();
    int pin = 0;
    for (int d = 1; d < 1024; d <<= 1) {
        int x = tmp[pin][t] + ((t >= d) ? tmp[pin][t - d] : 0);
        tmp[pin ^ 1][t] = x;
        pin ^= 1;
        __syncthreads();
    }
    int incl = tmp[pin][t];
    if (g < NN) offs[g] = incl - v;
    if (t == 1023) bsums[blockIdx.x] = incl;
}

__global__ __launch_bounds__(128) void scan2_kernel(int* __restrict__ bsums, int nb) {
    __shared__ int tmp[2][128];
    int t = threadIdx.x;
    int v = (t < nb) ? bsums[t] : 0;
    tmp[0][t] = v;
    __syncthreads();
    int pin = 0;
    for (int d = 1; d < 128; d <<= 1) {
        int x = tmp[pin][t] + ((t >= d) ? tmp[pin][t - d] : 0);
        tmp[pin ^ 1][t] = x;
        pin ^= 1;
        __syncthreads();
    }
    if (t < nb) bsums[t] = tmp[pin][t] - v;
}

// final offsets + per-node scatter cursors
__global__ __launch_bounds__(256) void scan3_kernel(int* __restrict__ offs, const int* __restrict__ bsums,
                                                    int* __restrict__ cursor) {
    int g = blockIdx.x * 256 + threadIdx.x;
    if (g < NN) {
        int o = offs[g] + bsums[g >> 10];
        offs[g] = o;
        cursor[g] = o;
    }
    if (g == 0) offs[NN] = NE;
}

// direct scatter: one 8B store per edge, 100K cursors (low contention, ~16 edges/node)
__global__ __launch_bounds__(256) void scatter_kernel(const int* __restrict__ src, const int* __restrict__ dst,
                                                      const float* __restrict__ ea, int* __restrict__ cursor,
                                                      int2* __restrict__ src_ea) {
    int e = blockIdx.x * 256 + threadIdx.x;
    if (e >= NE) return;
    int d = dst[e];
    int pos = atomicAdd(&cursor[d], 1);
    src_ea[pos] = make_int2(src[e], __float_as_int(ea[e]));
}

// ---------------- fused layer 0: BN-fold + gather-agg (half-wave) + GEMM + tanh + stats ----------------
// 32 nodes per 512-thread block. t1 -> t1_ws [NN][64] packed; per-channel stats -> dsum0/dsq0 (replicated)
__global__ __launch_bounds__(512) void gine0_kernel(const float* __restrict__ X,
        const int* __restrict__ offs, const int2* __restrict__ src_ea,
        const double* __restrict__ dsum, const double* __restrict__ dsq,
        const float* __restrict__ g, const float* __restrict__ b,
        const float* __restrict__ We, const float* __restrict__ be,
        const float* __restrict__ W, const float* __restrict__ bvec,
        float* __restrict__ t1_ws, double* __restrict__ dsum0, double* __restrict__ dsq0) {
    __shared__ __align__(16) float u_s[32][INC + 4];   // 16.9 KB
    __shared__ __align__(16) float w_s[DIM][INC + 4];  // 33.8 KB (reused for stats reduce)
    __shared__ float sc_s[INC], sh_s[INC];
    const int t = threadIdx.x;
    const int row0 = blockIdx.x * 32;
    bn_fold_rep<INC>(t, dsum, dsq, g, b, sc_s, sh_s);
    for (int i = t; i < INC * DIM; i += 512) {
        int k = i >> 6, c = i & 63;
        w_s[c][k] = W[i];
    }
    __syncthreads();
    // gather: 8 waves x 4 nodes; within a wave, halves process 2 edges at a time
    const int wid = t >> 6, l = t & 63;
    const int half = l >> 5;
    const int c4 = (l & 31) * 4;
    float4 sc = *(const float4*)(sc_s + c4);
    float4 sh = *(const float4*)(sh_s + c4);
    float4 wv = *(const float4*)(We + c4);
    float4 bv = *(const float4*)(be + c4);
    for (int nn = 0; nn < 4; ++nn) {
        int r = wid * 4 + nn;
        int n = row0 + r;
        float a0 = 0.f, a1 = 0.f, a2 = 0.f, a3 = 0.f;
        if (n < NN) {
            int beg = offs[n], end = offs[n + 1];
            for (int base = beg; base < end; base += 64) {
                int j = base + l;
                int2 p = (j < end) ? src_ea[j] : make_int2(0, 0);
                float avf = __int_as_float(p.y);
                int cnt = min(64, end - base);
                int tt = 0;
                for (; tt + 4 <= cnt; tt += 4) {
                    int e0 = tt + half, e1 = tt + 2 + half;
                    int s0 = __shfl(p.x, e0), s1 = __shfl(p.x, e1);
                    float av0 = __shfl(avf, e0), av1 = __shfl(avf, e1);
                    float4 x0 = *(const float4*)(X + (size_t)s0 * INC + c4);
                    float4 x1 = *(const float4*)(X + (size_t)s1 * INC + c4);
                    a0 += fmaxf(fmaf(x0.x, sc.x, sh.x) + fmaf(av0, wv.x, bv.x), 0.f);
                    a1 += fmaxf(fmaf(x0.y, sc.y, sh.y) + fmaf(av0, wv.y, bv.y), 0.f);
                    a2 += fmaxf(fmaf(x0.z, sc.z, sh.z) + fmaf(av0, wv.z, bv.z), 0.f);
                    a3 += fmaxf(fmaf(x0.w, sc.w, sh.w) + fmaf(av0, wv.w, bv.w), 0.f);
                    a0 += fmaxf(fmaf(x1.x, sc.x, sh.x) + fmaf(av1, wv.x, bv.x), 0.f);
                    a1 += fmaxf(fmaf(x1.y, sc.y, sh.y) + fmaf(av1, wv.y, bv.y), 0.f);
                    a2 += fmaxf(fmaf(x1.z, sc.z, sh.z) + fmaf(av1, wv.z, bv.z), 0.f);
                    a3 += fmaxf(fmaf(x1.w, sc.w, sh.w) + fmaf(av1, wv.w, bv.w), 0.f);
                }
                for (; tt < cnt; tt += 2) {
                    int e0 = tt + half;
                    int es = min(e0, cnt - 1);
                    int s0 = __shfl(p.x, es);
                    float av0 = __shfl(avf, es);
                    if (e0 < cnt) {
                        float4 x0 = *(const float4*)(X + (size_t)s0 * INC + c4);
                        a0 += fmaxf(fmaf(x0.x, sc.x, sh.x) + fmaf(av0, wv.x, bv.x), 0.f);
                        a1 += fmaxf(fmaf(x0.y, sc.y, sh.y) + fmaf(av0, wv.y, bv.y), 0.f);
                        a2 += fmaxf(fmaf(x0.z, sc.z, sh.z) + fmaf(av0, wv.z, bv.z), 0.f);
                        a3 += fmaxf(fmaf(x0.w, sc.w, sh.w) + fmaf(av0, wv.w, bv.w), 0.f);
                    }
                }
            }
        }
        a0 += __shfl_xor(a0, 32);
        a1 += __shfl_xor(a1, 32);
        a2 += __shfl_xor(a2, 32);
        a3 += __shfl_xor(a3, 32);
        if (half == 0) {
            if (n < NN) {
                float4 x = *(const float4*)(X + (size_t)n * INC + c4);
                a0 += fmaf(x.x, sc.x, sh.x);
                a1 += fmaf(x.y, sc.y, sh.y);
                a2 += fmaf(x.z, sc.z, sh.z);
                a3 += fmaf(x.w, sc.w, sh.w);
            }
            *(float4*)&u_s[r][c4] = make_float4(a0, a1, a2, a3);
        }
    }
    __syncthreads();
    // GEMM: 32x64 outputs, 512 threads -> 4 outputs each
    const int cc = t & 15;
    const int rg = t >> 4;                 // row 0..31
    float acc0 = bvec[cc], acc1 = bvec[cc + 16], acc2 = bvec[cc + 32], acc3 = bvec[cc + 48];
    #pragma unroll 4
    for (int k = 0; k < INC; k += 4) {
        float4 w0 = *(const float4*)&w_s[cc][k];
        float4 w1 = *(const float4*)&w_s[cc + 16][k];
        float4 w2 = *(const float4*)&w_s[cc + 32][k];
        float4 w3 = *(const float4*)&w_s[cc + 48][k];
        float4 u = *(const float4*)&u_s[rg][k];
        acc0 = fmaf(u.x, w0.x, fmaf(u.y, w0.y, fmaf(u.z, w0.z, fmaf(u.w, w0.w, acc0))));
        acc1 = fmaf(u.x, w1.x, fmaf(u.y, w1.y, fmaf(u.z, w1.z, fmaf(u.w, w1.w, acc1))));
        acc2 = fmaf(u.x, w2.x, fmaf(u.y, w2.y, fmaf(u.z, w2.z, fmaf(u.w, w2.w, acc2))));
        acc3 = fmaf(u.x, w3.x, fmaf(u.y, w3.y, fmaf(u.z, w3.z, fmaf(u.w, w3.w, acc3))));
    }
    int rr = row0 + rg;
    float t0 = tanhf(acc0), t1v = tanhf(acc1), t2v = tanhf(acc2), t3v = tanhf(acc3);
    if (rr < NN) {
        float* op = t1_ws + (size_t)rr * DIM;
        op[cc] = t0; op[cc + 16] = t1v; op[cc + 32] = t2v; op[cc + 48] = t3v;
    }
    // fused per-channel stats (reuse w_s as [32 rows][64 cols] x2)
    __syncthreads();
    float* red_s = (float*)w_s;
    float* red_q = red_s + 2048;
    bool ok = (rr < NN);
    red_s[rg * 64 + cc]      = ok ? t0 : 0.f;
    red_s[rg * 64 + cc + 16] = ok ? t1v : 0.f;
    red_s[rg * 64 + cc + 32] = ok ? t2v : 0.f;
    red_s[rg * 64 + cc + 48] = ok ? t3v : 0.f;
    red_q[rg * 64 + cc]      = ok ? t0 * t0 : 0.f;
    red_q[rg * 64 + cc + 16] = ok ? t1v * t1v : 0.f;
    red_q[rg * 64 + cc + 32] = ok ? t2v * t2v : 0.f;
    red_q[rg * 64 + cc + 48] = ok ? t3v * t3v : 0.f;
    __syncthreads();
    if (t < 64) {
        float s = 0.f, q = 0.f;
        #pragma unroll
        for (int i = 0; i < 32; i++) { s += red_s[i * 64 + t]; q += red_q[i * 64 + t]; }
        int rep = blockIdx.x & (NREP - 1);
        atomicAdd(&dsum0[rep * DIM + t], (double)s);
        atomicAdd(&dsq0[rep * DIM + t], (double)q);
    }
}

// ---------------- fused layer 1: BN(t1) on the fly + h1 write + gather-agg + GEMM + tanh + stats ----------------
// 64 nodes per 512-thread block. reads packed t1_ws; h1 -> out[:,0:64]; t2 -> out[:,64:128]
__global__ __launch_bounds__(512) void gine1_kernel(const float* __restrict__ t1_ws,
        const int* __restrict__ offs, const int2* __restrict__ src_ea,
        const double* __restrict__ dsum, const double* __restrict__ dsq,
        const float* __restrict__ g, const float* __restrict__ b,
        const float* __restrict__ We, const float* __restrict__ be,
        const float* __restrict__ W, const float* __restrict__ bvec,
        float* __restrict__ out, double* __restrict__ dsum1, double* __restrict__ dsq1) {
    __shared__ __align__(16) float u_s[64][DIM + 4];   // 17.4 KB
    __shared__ __align__(16) float w_s[DIM][DIM + 4];  // 17.4 KB (reused for stats reduce)
    __shared__ float sc_s[DIM], sh_s[DIM];
    const int t = threadIdx.x;
    const int row0 = blockIdx.x * 64;
    bn_fold_rep<DIM>(t, dsum, dsq, g, b, sc_s, sh_s);
    for (int i = t; i < DIM * DIM; i += 512) {
        int k = i >> 6, c = i & 63;
        w_s[c][k] = W[i];
    }
    __syncthreads();
    const int wid = t >> 6, l = t & 63;
    const int half = l >> 5;
    const int c2 = (l & 31) * 2;
    float2 wv = *(const float2*)(We + c2);
    float2 bv = *(const float2*)(be + c2);
    float2 sc2 = *(const float2*)(sc_s + c2);
    float2 sh2 = *(const float2*)(sh_s + c2);
    for (int nn = 0; nn < 8; ++nn) {
        int r = wid * 8 + nn;
        int n = row0 + r;
        float a0 = 0.f, a1 = 0.f;
        if (n < NN) {
            int beg = offs[n], end = offs[n + 1];
            for (int base = beg; base < end; base += 64) {
                int j = base + l;
                int2 p = (j < end) ? src_ea[j] : make_int2(0, 0);
                float avf = __int_as_float(p.y);
                int cnt = min(64, end - base);
                int tt = 0;
                for (; tt + 8 <= cnt; tt += 8) {
                    int e0 = tt + half, e1 = tt + 2 + half, e2 = tt + 4 + half, e3 = tt + 6 + half;
                    int s0 = __shfl(p.x, e0), s1 = __shfl(p.x, e1), s2 = __shfl(p.x, e2), s3 = __shfl(p.x, e3);
                    float av0 = __shfl(avf, e0), av1 = __shfl(avf, e1), av2 = __shfl(avf, e2), av3 = __shfl(avf, e3);
                    float2 h0 = *(const float2*)(t1_ws + (size_t)s0 * DIM + c2);
                    float2 hA = *(const float2*)(t1_ws + (size_t)s1 * DIM + c2);
                    float2 hB = *(const float2*)(t1_ws + (size_t)s2 * DIM + c2);
                    float2 hC = *(const float2*)(t1_ws + (size_t)s3 * DIM + c2);
                    a0 += fmaxf(fmaf(h0.x, sc2.x, sh2.x) + fmaf(av0, wv.x, bv.x), 0.f);
                    a1 += fmaxf(fmaf(h0.y, sc2.y, sh2.y) + fmaf(av0, wv.y, bv.y), 0.f);
                    a0 += fmaxf(fmaf(hA.x, sc2.x, sh2.x) + fmaf(av1, wv.x, bv.x), 0.f);
                    a1 += fmaxf(fmaf(hA.y, sc2.y, sh2.y) + fmaf(av1, wv.y, bv.y), 0.f);
                    a0 += fmaxf(fmaf(hB.x, sc2.x, sh2.x) + fmaf(av2, wv.x, bv.x), 0.f);
                    a1 += fmaxf(fmaf(hB.y, sc2.y, sh2.y) + fmaf(av2, wv.y, bv.y), 0.f);
                    a0 += fmaxf(fmaf(hC.x, sc2.x, sh2.x) + fmaf(av3, wv.x, bv.x), 0.f);
                    a1 += fmaxf(fmaf(hC.y, sc2.y, sh2.y) + fmaf(av3, wv.y, bv.y), 0.f);
                }
                for (; tt < cnt; tt += 2) {
                    int e0 = tt + half;
                    int es = min(e0, cnt - 1);
                    int s0 = __shfl(p.x, es);
                    float av0 = __shfl(avf, es);
                    if (e0 < cnt) {
                        float2 h0 = *(const float2*)(t1_ws + (size_t)s0 * DIM + c2);
                        a0 += fmaxf(fmaf(h0.x, sc2.x, sh2.x) + fmaf(av0, wv.x, bv.x), 0.f);
                        a1 += fmaxf(fmaf(h0.y, sc2.y, sh2.y) + fmaf(av0, wv.y, bv.y), 0.f);
                    }
                }
            }
        }
        a0 += __shfl_xor(a0, 32);
        a1 += __shfl_xor(a1, 32);
        if (half == 0) {
            if (n < NN) {
                float2 h = *(const float2*)(t1_ws + (size_t)n * DIM + c2);
                float h1x = fmaf(h.x, sc2.x, sh2.x);
                float h1y = fmaf(h.y, sc2.y, sh2.y);
                *(float2*)(out + (size_t)n * 192 + c2) = make_float2(h1x, h1y);   // h1
                a0 += h1x;
                a1 += h1y;
            }
            *(float2*)&u_s[r][c2] = make_float2(a0, a1);
        }
    }
    __syncthreads();
    // GEMM: 64x64 outputs, 512 threads -> 8 outputs each (2 rows x 4 cols)
    const int cc = t & 15;
    const int r0 = (t >> 4) * 2;
    float acc[2][4];
    #pragma unroll
    for (int j = 0; j < 4; j++) {
        float bj = bvec[cc + 16 * j];
        acc[0][j] = bj; acc[1][j] = bj;
    }
    #pragma unroll 4
    for (int k = 0; k < DIM; k += 4) {
        float4 w0 = *(const float4*)&w_s[cc][k];
        float4 w1 = *(const float4*)&w_s[cc + 16][k];
        float4 w2 = *(const float4*)&w_s[cc + 32][k];
        float4 w3 = *(const float4*)&w_s[cc + 48][k];
        #pragma unroll
        for (int i = 0; i < 2; i++) {
            float4 u = *(const float4*)&u_s[r0 + i][k];
            acc[i][0] = fmaf(u.x, w0.x, fmaf(u.y, w0.y, fmaf(u.z, w0.z, fmaf(u.w, w0.w, acc[i][0]))));
            acc[i][1] = fmaf(u.x, w1.x, fmaf(u.y, w1.y, fmaf(u.z, w1.z, fmaf(u.w, w1.w, acc[i][1]))));
            acc[i][2] = fmaf(u.x, w2.x, fmaf(u.y, w2.y, fmaf(u.z, w2.z, fmaf(u.w, w2.w, acc[i][2]))));
            acc[i][3] = fmaf(u.x, w3.x, fmaf(u.y, w3.y, fmaf(u.z, w3.z, fmaf(u.w, w3.w, acc[i][3]))));
        }
    }
    float tv[2][4];
    #pragma unroll
    for (int i = 0; i < 2; i++) {
        int rr = row0 + r0 + i;
        #pragma unroll
        for (int j = 0; j < 4; j++) tv[i][j] = tanhf(acc[i][j]);
        if (rr < NN) {
            float* op = out + (size_t)rr * 192 + 64;
            #pragma unroll
            for (int j = 0; j < 4; j++) op[cc + 16 * j] = tv[i][j];
        }
    }
    // fused per-channel stats of t2 (reuse w_s as [32 rowgrps][64 cols] x2)
    __syncthreads();
    float* red_s = (float*)w_s;
    float* red_q = red_s + 2048;
    const int rgp = t >> 4;
    bool ok0 = (row0 + r0 < NN), ok1 = (row0 + r0 + 1 < NN);
    #pragma unroll
    for (int j = 0; j < 4; j++) {
        float v0 = ok0 ? tv[0][j] : 0.f;
        float v1 = ok1 ? tv[1][j] : 0.f;
        red_s[rgp * 64 + cc + 16 * j] = v0 + v1;
        red_q[rgp * 64 + cc + 16 * j] = v0 * v0 + v1 * v1;
    }
    __syncthreads();
    if (t < 64) {
        float s = 0.f, q = 0.f;
        #pragma unroll
        for (int i = 0; i < 32; i++) { s += red_s[i * 64 + t]; q += red_q[i * 64 + t]; }
        int rep = blockIdx.x & (NREP - 1);
        atomicAdd(&dsum1[rep * DIM + t], (double)s);
        atomicAdd(&dsq1[rep * DIM + t], (double)q);
    }
}

// ---------------- fused: finalize1 + h2 = BN(t2) in place + h3 = tanh(h2 @ Wfc) ----------------
__global__ __launch_bounds__(256) void fc_kernel(float* __restrict__ io,
        const double* __restrict__ dsum, const double* __restrict__ dsq,
        const float* __restrict__ g, const float* __restrict__ b,
        const float* __restrict__ W) {
    __shared__ __align__(16) float u_s[64][DIM + 4];
    __shared__ __align__(16) float w_s[DIM][DIM + 4];
    __shared__ float sc_s[DIM], sh_s[DIM];
    const int t = threadIdx.x;
    const int row0 = blockIdx.x * 64;
    bn_fold_rep<DIM>(t, dsum, dsq, g, b, sc_s, sh_s);
    __syncthreads();
    for (int i = t; i < DIM * DIM; i += 256) {
        int k = i >> 6, c = i & 63;
        w_s[c][k] = W[i];
    }
    for (int i = t; i < 64 * DIM; i += 256) {
        int r = i >> 6, k = i & 63;
        int rr = row0 + r;
        float v = 0.f;
        if (rr < NN) {
            size_t idx = (size_t)rr * 192 + 64 + k;
            v = fmaf(io[idx], sc_s[k], sh_s[k]);
            io[idx] = v;                       // h2
        }
        u_s[r][k] = v;
    }
    __syncthreads();
    const int cc = t & 15;
    const int r0 = (t >> 4) << 2;
    float acc[4][4];
    #pragma unroll
    for (int j = 0; j < 4; j++) { acc[0][j] = 0.f; acc[1][j] = 0.f; acc[2][j] = 0.f; acc[3][j] = 0.f; }
    #pragma unroll 4
    for (int k = 0; k < DIM; k += 4) {
        float4 w0 = *(const float4*)&w_s[cc][k];
        float4 w1 = *(const float4*)&w_s[cc + 16][k];
        float4 w2 = *(const float4*)&w_s[cc + 32][k];
        float4 w3 = *(const float4*)&w_s[cc + 48][k];
        #pragma unroll
        for (int i = 0; i < 4; i++) {
            float4 u = *(const float4*)&u_s[r0 + i][k];
            acc[i][0] = fmaf(u.x, w0.x, fmaf(u.y, w0.y, fmaf(u.z, w0.z, fmaf(u.w, w0.w, acc[i][0]))));
            acc[i][1] = fmaf(u.x, w1.x, fmaf(u.y, w1.y, fmaf(u.z, w1.z, fmaf(u.w, w1.w, acc[i][1]))));
            acc[i][2] = fmaf(u.x, w2.x, fmaf(u.y, w2.y, fmaf(u.z, w2.z, fmaf(u.w, w2.w, acc[i][2]))));
            acc[i][3] = fmaf(u.x, w3.x, fmaf(u.y, w3.y, fmaf(u.z, w3.z, fmaf(u.w, w3.w, acc[i][3]))));
        }
    }
    #pragma unroll
    for (int i = 0; i < 4; i++) {
        int rr = row0 + r0 + i;
        if (rr < NN) {
            #pragma unroll
            for (int j = 0; j < 4; j++)
                io[(size_t)rr * 192 + 128 + cc + 16 * j] = tanhf(acc[i][j]);
        }
    }
}

extern "C" void kernel_launch(void* const* d_in, const int* in_sizes, int n_in,
                              void* d_out, int out_size, void* d_ws, size_t ws_size,
                              hipStream_t stream) {
    const float* X      = (const float*)d_in[0];
    const int*   ei     = (const int*)  d_in[1];
    const float* ea     = (const float*)d_in[2];
    const float* bng    = (const float*)d_in[3];
    const float* bnb    = (const float*)d_in[4];
    const float* We0    = (const float*)d_in[5];
    const float* be0    = (const float*)d_in[6];
    const float* W0     = (const float*)d_in[7];
    const float* b0     = (const float*)d_in[8];
    const float* bn0g   = (const float*)d_in[9];
    const float* bn0b   = (const float*)d_in[10];
    const float* We1    = (const float*)d_in[11];
    const float* be1    = (const float*)d_in[12];
    const float* W1     = (const float*)d_in[13];
    const float* b1     = (const float*)d_in[14];
    const float* bn1g   = (const float*)d_in[15];
    const float* bn1b   = (const float*)d_in[16];
    const float* Wfc    = (const float*)d_in[17];

    const int* src = ei;
    const int* dst = ei + NE;
    float* out = (float*)d_out;

    // ---- workspace layout (~39 MB) ----
    int2*  src_ea   = (int2*)d_ws;                      // NE
    float* t1_ws    = (float*)(src_ea + NE);            // NN*DIM
    int*   counts   = (int*)(t1_ws + (size_t)NN * DIM); // NN
    int*   offs     = counts + NN;                      // NN+1
    int*   cursor   = offs + NN + 1;                    // NN
    int*   bsums    = cursor + NN;                      // 128
    double* dstats = (double*)(((uintptr_t)(bsums + 128) + 15) & ~(uintptr_t)15);
    // replicated stats: in = NREP*128 x2; layer0/1 = NREP*64 x2 each
    double* dsum_in = dstats;                          // NREP*128
    double* dsq_in  = dsum_in + NREP * INC;            // NREP*128
    double* dsum0   = dsq_in + NREP * INC;             // NREP*64
    double* dsq0    = dsum0 + NREP * DIM;              // NREP*64
    double* dsum1   = dsq0 + NREP * DIM;               // NREP*64
    double* dsq1    = dsum1 + NREP * DIM;              // NREP*64
    const size_t nstats = (size_t)NREP * (2 * INC + 4 * DIM);

    hipMemsetAsync(counts, 0, NN * sizeof(int), stream);
    hipMemsetAsync(dstats, 0, nstats * sizeof(double), stream);

    // fused input-BN stats + dst histogram
    stats_hist_kernel<<<SB + (NE + 255) / 256, 256, 0, stream>>>(X, dst, counts, dsum_in, dsq_in);

    // CSR build (shared by both layers)
    const int NB = (NN + 1023) / 1024;   // 98
    scan1_kernel<<<NB, 1024, 0, stream>>>(counts, offs, bsums);
    scan2_kernel<<<1, 128, 0, stream>>>(bsums, NB);
    scan3_kernel<<<(NN + 255) / 256, 256, 0, stream>>>(offs, bsums, cursor);
    scatter_kernel<<<NE / 256, 256, 0, stream>>>(src, dst, ea, cursor, src_ea);

    // layer 0 (fused finalize_in + agg + GEMM + stats0)
    gine0_kernel<<<(NN + 31) / 32, 512, 0, stream>>>(X, offs, src_ea, dsum_in, dsq_in, bng, bnb,
                                                     We0, be0, W0, b0, t1_ws, dsum0, dsq0);

    // layer 1 (fused finalize0 + BN-on-fly + h1 write + agg + GEMM + stats1)
    gine1_kernel<<<(NN + 63) / 64, 512, 0, stream>>>(t1_ws, offs, src_ea, dsum0, dsq0, bn0g, bn0b,
                                                     We1, be1, W1, b1, out, dsum1, dsq1);

    // h2 (in place) + h3 (fused finalize1)
    fc_kernel<<<(NN + 63) / 64, 256, 0, stream>>>(out, dsum1, dsq1, bn1g, bn1b, Wfc);
}

// Round 8
// 496.462 us; speedup vs baseline: 1.7655x; 1.0290x over previous
//
#include <hip/hip_runtime.h>
#include <hip/hip_fp16.h>
#include <math.h>
#include <stdint.h>

#define NN 100000
#define NE 1600000
#define INC 128
#define DIM 64
#define EPS 1e-5f
#define SB 512   // stats blocks inside fused stats+hist kernel
#define NREP 8   // stats accumulator replicas (atomic-contention spreading)

struct __align__(8) half4 { __half2 a, b; };

// fused: blocks [0,SB) do X stats (C=128) in f64; blocks [SB,...) do dst histogram
__global__ __launch_bounds__(256) void stats_hist_kernel(const float* __restrict__ X,
        const int* __restrict__ dst, int* __restrict__ counts,
        double* __restrict__ sum_out, double* __restrict__ sq_out) {
    __shared__ double ls[256], lq[256];
    if (blockIdx.x < SB) {
        int c  = threadIdx.x & 127;
        int rl = threadIdx.x >> 7;           // 2 rows per block step
        int row = blockIdx.x * 2 + rl;
        const int rstride = SB * 2;
        double s = 0.0, q = 0.0;
        for (int r = row; r < NN; r += rstride) {
            double v = (double)X[(size_t)r * INC + c];
            s += v; q += v * v;
        }
        ls[threadIdx.x] = s; lq[threadIdx.x] = q;
        __syncthreads();
        if (rl == 0) {
            s += ls[128 + c]; q += lq[128 + c];
            int rep = blockIdx.x & (NREP - 1);
            atomicAdd(&sum_out[rep * INC + c], s);
            atomicAdd(&sq_out[rep * INC + c], q);
        }
    } else {
        int e = (blockIdx.x - SB) * 256 + threadIdx.x;
        if (e < NE) atomicAdd(&counts[dst[e]], 1);
    }
}

// BN scale/shift from NREP-replicated f64 stats
template<int C>
__device__ inline void bn_fold_rep(int t, const double* dsum, const double* dsq,
                                   const float* g, const float* b, float* sc_s, float* sh_s) {
    if (t < C) {
        double s = 0.0, q = 0.0;
        #pragma unroll
        for (int r = 0; r < NREP; r++) { s += dsum[r * C + t]; q += dsq[r * C + t]; }
        double m = s / (double)NN;
        double v = q / (double)NN - m * m;
        double sc = (double)g[t] / sqrt(v + (double)EPS);
        sc_s[t] = (float)sc;
        sh_s[t] = (float)((double)b[t] - m * sc);
    }
}

// x̂ = BN(X) precomputed to fp16 [NN][128] (halves per-edge gather bytes in gine0)
__global__ __launch_bounds__(256) void xhat_half_kernel(const float* __restrict__ X,
        const double* __restrict__ dsum, const double* __restrict__ dsq,
        const float* __restrict__ g, const float* __restrict__ b,
        __half* __restrict__ Xh) {
    __shared__ float sc_s[INC], sh_s[INC];
    bn_fold_rep<INC>(threadIdx.x, dsum, dsq, g, b, sc_s, sh_s);
    __syncthreads();
    size_t i = (size_t)blockIdx.x * 256 + threadIdx.x;   // one float4 per thread
    size_t e4 = i * 4;
    if (e4 >= (size_t)NN * INC) return;
    int c = (int)(e4 & 127);
    float4 x = *(const float4*)(X + e4);
    half4 h;
    h.a = __floats2half2_rn(fmaf(x.x, sc_s[c], sh_s[c]), fmaf(x.y, sc_s[c + 1], sh_s[c + 1]));
    h.b = __floats2half2_rn(fmaf(x.z, sc_s[c + 2], sh_s[c + 2]), fmaf(x.w, sc_s[c + 3], sh_s[c + 3]));
    *(half4*)(Xh + e4) = h;
}

// ---------------- CSR build: scan ----------------
__global__ __launch_bounds__(1024) void scan1_kernel(const int* __restrict__ counts,
                                                     int* __restrict__ offs, int* __restrict__ bsums) {
    __shared__ int tmp[2][1024];
    int t = threadIdx.x;
    int g = blockIdx.x * 1024 + t;
    int v = (g < NN) ? counts[g] : 0;
    tmp[0][t] = v;
    __syncthreads();
    int pin = 0;
    for (int d = 1; d < 1024; d <<= 1) {
        int x = tmp[pin][t] + ((t >= d) ? tmp[pin][t - d] : 0);
        tmp[pin ^ 1][t] = x;
        pin ^= 1;
        __syncthreads();
    }
    int incl = tmp[pin][t];
    if (g < NN) offs[g] = incl - v;
    if (t == 1023) bsums[blockIdx.x] = incl;
}

__global__ __launch_bounds__(128) void scan2_kernel(int* __restrict__ bsums, int nb) {
    __shared__ int tmp[2][128];
    int t = threadIdx.x;
    int v = (t < nb) ? bsums[t] : 0;
    tmp[0][t] = v;
    __syncthreads();
    int pin = 0;
    for (int d = 1; d < 128; d <<= 1) {
        int x = tmp[pin][t] + ((t >= d) ? tmp[pin][t - d] : 0);
        tmp[pin ^ 1][t] = x;
        pin ^= 1;
        __syncthreads();
    }
    if (t < nb) bsums[t] = tmp[pin][t] - v;
}

// final offsets + per-node scatter cursors
__global__ __launch_bounds__(256) void scan3_kernel(int* __restrict__ offs, const int* __restrict__ bsums,
                                                    int* __restrict__ cursor) {
    int g = blockIdx.x * 256 + threadIdx.x;
    if (g < NN) {
        int o = offs[g] + bsums[g >> 10];
        offs[g] = o;
        cursor[g] = o;
    }
    if (g == 0) offs[NN] = NE;
}

// direct scatter: one 8B store per edge, 100K cursors (low contention, ~16 edges/node)
__global__ __launch_bounds__(256) void scatter_kernel(const int* __restrict__ src, const int* __restrict__ dst,
                                                      const float* __restrict__ ea, int* __restrict__ cursor,
                                                      int2* __restrict__ src_ea) {
    int e = blockIdx.x * 256 + threadIdx.x;
    if (e >= NE) return;
    int d = dst[e];
    int pos = atomicAdd(&cursor[d], 1);
    src_ea[pos] = make_int2(src[e], __float_as_int(ea[e]));
}

// ---------------- fused layer 0: gather-agg (fp16 x̂, half-wave) + GEMM + tanh + stats ----------------
// 32 nodes per 512-thread block. t1 -> t1_ws [NN][64] packed; per-channel stats -> dsum0/dsq0 (replicated)
__global__ __launch_bounds__(512) void gine0_kernel(const float* __restrict__ X,
        const __half* __restrict__ Xh,
        const int* __restrict__ offs, const int2* __restrict__ src_ea,
        const double* __restrict__ dsum, const double* __restrict__ dsq,
        const float* __restrict__ g, const float* __restrict__ b,
        const float* __restrict__ We, const float* __restrict__ be,
        const float* __restrict__ W, const float* __restrict__ bvec,
        float* __restrict__ t1_ws, double* __restrict__ dsum0, double* __restrict__ dsq0) {
    __shared__ __align__(16) float u_s[32][INC + 4];   // 16.9 KB
    __shared__ __align__(16) float w_s[DIM][INC + 4];  // 33.8 KB (reused for stats reduce)
    __shared__ float sc_s[INC], sh_s[INC];
    const int t = threadIdx.x;
    const int row0 = blockIdx.x * 32;
    bn_fold_rep<INC>(t, dsum, dsq, g, b, sc_s, sh_s);
    for (int i = t; i < INC * DIM; i += 512) {
        int k = i >> 6, c = i & 63;
        w_s[c][k] = W[i];
    }
    __syncthreads();
    // gather: 8 waves x 4 nodes; within a wave, halves process 2 edges at a time
    const int wid = t >> 6, l = t & 63;
    const int half = l >> 5;
    const int c4 = (l & 31) * 4;
    float4 sc = *(const float4*)(sc_s + c4);
    float4 sh = *(const float4*)(sh_s + c4);
    float4 wv = *(const float4*)(We + c4);
    float4 bv = *(const float4*)(be + c4);
    for (int nn = 0; nn < 4; ++nn) {
        int r = wid * 4 + nn;
        int n = row0 + r;
        float a0 = 0.f, a1 = 0.f, a2 = 0.f, a3 = 0.f;
        if (n < NN) {
            int beg = offs[n], end = offs[n + 1];
            for (int base = beg; base < end; base += 64) {
                int j = base + l;
                int2 p = (j < end) ? src_ea[j] : make_int2(0, 0);
                float avf = __int_as_float(p.y);
                int cnt = min(64, end - base);
                int tt = 0;
                for (; tt + 4 <= cnt; tt += 4) {
                    int e0 = tt + half, e1 = tt + 2 + half;
                    int s0 = __shfl(p.x, e0), s1 = __shfl(p.x, e1);
                    float av0 = __shfl(avf, e0), av1 = __shfl(avf, e1);
                    half4 v0 = *(const half4*)(Xh + (size_t)s0 * INC + c4);
                    half4 v1 = *(const half4*)(Xh + (size_t)s1 * INC + c4);
                    float2 f00 = __half22float2(v0.a), f01 = __half22float2(v0.b);
                    float2 f10 = __half22float2(v1.a), f11 = __half22float2(v1.b);
                    a0 += fmaxf(f00.x + fmaf(av0, wv.x, bv.x), 0.f);
                    a1 += fmaxf(f00.y + fmaf(av0, wv.y, bv.y), 0.f);
                    a2 += fmaxf(f01.x + fmaf(av0, wv.z, bv.z), 0.f);
                    a3 += fmaxf(f01.y + fmaf(av0, wv.w, bv.w), 0.f);
                    a0 += fmaxf(f10.x + fmaf(av1, wv.x, bv.x), 0.f);
                    a1 += fmaxf(f10.y + fmaf(av1, wv.y, bv.y), 0.f);
                    a2 += fmaxf(f11.x + fmaf(av1, wv.z, bv.z), 0.f);
                    a3 += fmaxf(f11.y + fmaf(av1, wv.w, bv.w), 0.f);
                }
                for (; tt < cnt; tt += 2) {
                    int e0 = tt + half;
                    int es = min(e0, cnt - 1);
                    int s0 = __shfl(p.x, es);
                    float av0 = __shfl(avf, es);
                    if (e0 < cnt) {
                        half4 v0 = *(const half4*)(Xh + (size_t)s0 * INC + c4);
                        float2 f00 = __half22float2(v0.a), f01 = __half22float2(v0.b);
                        a0 += fmaxf(f00.x + fmaf(av0, wv.x, bv.x), 0.f);
                        a1 += fmaxf(f00.y + fmaf(av0, wv.y, bv.y), 0.f);
                        a2 += fmaxf(f01.x + fmaf(av0, wv.z, bv.z), 0.f);
                        a3 += fmaxf(f01.y + fmaf(av0, wv.w, bv.w), 0.f);
                    }
                }
            }
        }
        a0 += __shfl_xor(a0, 32);
        a1 += __shfl_xor(a1, 32);
        a2 += __shfl_xor(a2, 32);
        a3 += __shfl_xor(a3, 32);
        if (half == 0) {
            if (n < NN) {
                // self term from f32 X for precision
                float4 x = *(const float4*)(X + (size_t)n * INC + c4);
                a0 += fmaf(x.x, sc.x, sh.x);
                a1 += fmaf(x.y, sc.y, sh.y);
                a2 += fmaf(x.z, sc.z, sh.z);
                a3 += fmaf(x.w, sc.w, sh.w);
            }
            *(float4*)&u_s[r][c4] = make_float4(a0, a1, a2, a3);
        }
    }
    __syncthreads();
    // GEMM: 32x64 outputs, 512 threads -> 4 outputs each
    const int cc = t & 15;
    const int rg = t >> 4;                 // row 0..31
    float acc0 = bvec[cc], acc1 = bvec[cc + 16], acc2 = bvec[cc + 32], acc3 = bvec[cc + 48];
    #pragma unroll 4
    for (int k = 0; k < INC; k += 4) {
        float4 w0 = *(const float4*)&w_s[cc][k];
        float4 w1 = *(const float4*)&w_s[cc + 16][k];
        float4 w2 = *(const float4*)&w_s[cc + 32][k];
        float4 w3 = *(const float4*)&w_s[cc + 48][k];
        float4 u = *(const float4*)&u_s[rg][k];
        acc0 = fmaf(u.x, w0.x, fmaf(u.y, w0.y, fmaf(u.z, w0.z, fmaf(u.w, w0.w, acc0))));
        acc1 = fmaf(u.x, w1.x, fmaf(u.y, w1.y, fmaf(u.z, w1.z, fmaf(u.w, w1.w, acc1))));
        acc2 = fmaf(u.x, w2.x, fmaf(u.y, w2.y, fmaf(u.z, w2.z, fmaf(u.w, w2.w, acc2))));
        acc3 = fmaf(u.x, w3.x, fmaf(u.y, w3.y, fmaf(u.z, w3.z, fmaf(u.w, w3.w, acc3))));
    }
    int rr = row0 + rg;
    float t0 = tanhf(acc0), t1v = tanhf(acc1), t2v = tanhf(acc2), t3v = tanhf(acc3);
    if (rr < NN) {
        float* op = t1_ws + (size_t)rr * DIM;
        op[cc] = t0; op[cc + 16] = t1v; op[cc + 32] = t2v; op[cc + 48] = t3v;
    }
    // fused per-channel stats (reuse w_s as [32 rows][64 cols] x2)
    __syncthreads();
    float* red_s = (float*)w_s;
    float* red_q = red_s + 2048;
    bool ok = (rr < NN);
    red_s[rg * 64 + cc]      = ok ? t0 : 0.f;
    red_s[rg * 64 + cc + 16] = ok ? t1v : 0.f;
    red_s[rg * 64 + cc + 32] = ok ? t2v : 0.f;
    red_s[rg * 64 + cc + 48] = ok ? t3v : 0.f;
    red_q[rg * 64 + cc]      = ok ? t0 * t0 : 0.f;
    red_q[rg * 64 + cc + 16] = ok ? t1v * t1v : 0.f;
    red_q[rg * 64 + cc + 32] = ok ? t2v * t2v : 0.f;
    red_q[rg * 64 + cc + 48] = ok ? t3v * t3v : 0.f;
    __syncthreads();
    if (t < 64) {
        float s = 0.f, q = 0.f;
        #pragma unroll
        for (int i = 0; i < 32; i++) { s += red_s[i * 64 + t]; q += red_q[i * 64 + t]; }
        int rep = blockIdx.x & (NREP - 1);
        atomicAdd(&dsum0[rep * DIM + t], (double)s);
        atomicAdd(&dsq0[rep * DIM + t], (double)q);
    }
}

// ---------------- fused layer 1: BN(t1) on the fly + h1 write + gather-agg + GEMM + tanh + stats ----------------
// 64 nodes per 512-thread block. reads packed t1_ws; h1 -> out[:,0:64]; t2 -> out[:,64:128]
__global__ __launch_bounds__(512) void gine1_kernel(const float* __restrict__ t1_ws,
        const int* __restrict__ offs, const int2* __restrict__ src_ea,
        const double* __restrict__ dsum, const double* __restrict__ dsq,
        const float* __restrict__ g, const float* __restrict__ b,
        const float* __restrict__ We, const float* __restrict__ be,
        const float* __restrict__ W, const float* __restrict__ bvec,
        float* __restrict__ out, double* __restrict__ dsum1, double* __restrict__ dsq1) {
    __shared__ __align__(16) float u_s[64][DIM + 4];   // 17.4 KB
    __shared__ __align__(16) float w_s[DIM][DIM + 4];  // 17.4 KB (reused for stats reduce)
    __shared__ float sc_s[DIM], sh_s[DIM];
    const int t = threadIdx.x;
    const int row0 = blockIdx.x * 64;
    bn_fold_rep<DIM>(t, dsum, dsq, g, b, sc_s, sh_s);
    for (int i = t; i < DIM * DIM; i += 512) {
        int k = i >> 6, c = i & 63;
        w_s[c][k] = W[i];
    }
    __syncthreads();
    const int wid = t >> 6, l = t & 63;
    const int half = l >> 5;
    const int c2 = (l & 31) * 2;
    float2 wv = *(const float2*)(We + c2);
    float2 bv = *(const float2*)(be + c2);
    float2 sc2 = *(const float2*)(sc_s + c2);
    float2 sh2 = *(const float2*)(sh_s + c2);
    for (int nn = 0; nn < 8; ++nn) {
        int r = wid * 8 + nn;
        int n = row0 + r;
        float a0 = 0.f, a1 = 0.f;
        if (n < NN) {
            int beg = offs[n], end = offs[n + 1];
            for (int base = beg; base < end; base += 64) {
                int j = base + l;
                int2 p = (j < end) ? src_ea[j] : make_int2(0, 0);
                float avf = __int_as_float(p.y);
                int cnt = min(64, end - base);
                int tt = 0;
                for (; tt + 8 <= cnt; tt += 8) {
                    int e0 = tt + half, e1 = tt + 2 + half, e2 = tt + 4 + half, e3 = tt + 6 + half;
                    int s0 = __shfl(p.x, e0), s1 = __shfl(p.x, e1), s2 = __shfl(p.x, e2), s3 = __shfl(p.x, e3);
                    float av0 = __shfl(avf, e0), av1 = __shfl(avf, e1), av2 = __shfl(avf, e2), av3 = __shfl(avf, e3);
                    float2 h0 = *(const float2*)(t1_ws + (size_t)s0 * DIM + c2);
                    float2 hA = *(const float2*)(t1_ws + (size_t)s1 * DIM + c2);
                    float2 hB = *(const float2*)(t1_ws + (size_t)s2 * DIM + c2);
                    float2 hC = *(const float2*)(t1_ws + (size_t)s3 * DIM + c2);
                    a0 += fmaxf(fmaf(h0.x, sc2.x, sh2.x) + fmaf(av0, wv.x, bv.x), 0.f);
                    a1 += fmaxf(fmaf(h0.y, sc2.y, sh2.y) + fmaf(av0, wv.y, bv.y), 0.f);
                    a0 += fmaxf(fmaf(hA.x, sc2.x, sh2.x) + fmaf(av1, wv.x, bv.x), 0.f);
                    a1 += fmaxf(fmaf(hA.y, sc2.y, sh2.y) + fmaf(av1, wv.y, bv.y), 0.f);
                    a0 += fmaxf(fmaf(hB.x, sc2.x, sh2.x) + fmaf(av2, wv.x, bv.x), 0.f);
                    a1 += fmaxf(fmaf(hB.y, sc2.y, sh2.y) + fmaf(av2, wv.y, bv.y), 0.f);
                    a0 += fmaxf(fmaf(hC.x, sc2.x, sh2.x) + fmaf(av3, wv.x, bv.x), 0.f);
                    a1 += fmaxf(fmaf(hC.y, sc2.y, sh2.y) + fmaf(av3, wv.y, bv.y), 0.f);
                }
                for (; tt < cnt; tt += 2) {
                    int e0 = tt + half;
                    int es = min(e0, cnt - 1);
                    int s0 = __shfl(p.x, es);
                    float av0 = __shfl(avf, es);
                    if (e0 < cnt) {
                        float2 h0 = *(const float2*)(t1_ws + (size_t)s0 * DIM + c2);
                        a0 += fmaxf(fmaf(h0.x, sc2.x, sh2.x) + fmaf(av0, wv.x, bv.x), 0.f);
                        a1 += fmaxf(fmaf(h0.y, sc2.y, sh2.y) + fmaf(av0, wv.y, bv.y), 0.f);
                    }
                }
            }
        }
        a0 += __shfl_xor(a0, 32);
        a1 += __shfl_xor(a1, 32);
        if (half == 0) {
            if (n < NN) {
                float2 h = *(const float2*)(t1_ws + (size_t)n * DIM + c2);
                float h1x = fmaf(h.x, sc2.x, sh2.x);
                float h1y = fmaf(h.y, sc2.y, sh2.y);
                *(float2*)(out + (size_t)n * 192 + c2) = make_float2(h1x, h1y);   // h1
                a0 += h1x;
                a1 += h1y;
            }
            *(float2*)&u_s[r][c2] = make_float2(a0, a1);
        }
    }
    __syncthreads();
    // GEMM: 64x64 outputs, 512 threads -> 8 outputs each (2 rows x 4 cols)
    const int cc = t & 15;
    const int r0 = (t >> 4) * 2;
    float acc[2][4];
    #pragma unroll
    for (int j = 0; j < 4; j++) {
        float bj = bvec[cc + 16 * j];
        acc[0][j] = bj; acc[1][j] = bj;
    }
    #pragma unroll 4
    for (int k = 0; k < DIM; k += 4) {
        float4 w0 = *(const float4*)&w_s[cc][k];
        float4 w1 = *(const float4*)&w_s[cc + 16][k];
        float4 w2 = *(const float4*)&w_s[cc + 32][k];
        float4 w3 = *(const float4*)&w_s[cc + 48][k];
        #pragma unroll
        for (int i = 0; i < 2; i++) {
            float4 u = *(const float4*)&u_s[r0 + i][k];
            acc[i][0] = fmaf(u.x, w0.x, fmaf(u.y, w0.y, fmaf(u.z, w0.z, fmaf(u.w, w0.w, acc[i][0]))));
            acc[i][1] = fmaf(u.x, w1.x, fmaf(u.y, w1.y, fmaf(u.z, w1.z, fmaf(u.w, w1.w, acc[i][1]))));
            acc[i][2] = fmaf(u.x, w2.x, fmaf(u.y, w2.y, fmaf(u.z, w2.z, fmaf(u.w, w2.w, acc[i][2]))));
            acc[i][3] = fmaf(u.x, w3.x, fmaf(u.y, w3.y, fmaf(u.z, w3.z, fmaf(u.w, w3.w, acc[i][3]))));
        }
    }
    float tv[2][4];
    #pragma unroll
    for (int i = 0; i < 2; i++) {
        int rr = row0 + r0 + i;
        #pragma unroll
        for (int j = 0; j < 4; j++) tv[i][j] = tanhf(acc[i][j]);
        if (rr < NN) {
            float* op = out + (size_t)rr * 192 + 64;
            #pragma unroll
            for (int j = 0; j < 4; j++) op[cc + 16 * j] = tv[i][j];
        }
    }
    // fused per-channel stats of t2 (reuse w_s as [32 rowgrps][64 cols] x2)
    __syncthreads();
    float* red_s = (float*)w_s;
    float* red_q = red_s + 2048;
    const int rgp = t >> 4;
    bool ok0 = (row0 + r0 < NN), ok1 = (row0 + r0 + 1 < NN);
    #pragma unroll
    for (int j = 0; j < 4; j++) {
        float v0 = ok0 ? tv[0][j] : 0.f;
        float v1 = ok1 ? tv[1][j] : 0.f;
        red_s[rgp * 64 + cc + 16 * j] = v0 + v1;
        red_q[rgp * 64 + cc + 16 * j] = v0 * v0 + v1 * v1;
    }
    __syncthreads();
    if (t < 64) {
        float s = 0.f, q = 0.f;
        #pragma unroll
        for (int i = 0; i < 32; i++) { s += red_s[i * 64 + t]; q += red_q[i * 64 + t]; }
        int rep = blockIdx.x & (NREP - 1);
        atomicAdd(&dsum1[rep * DIM + t], (double)s);
        atomicAdd(&dsq1[rep * DIM + t], (double)q);
    }
}

// ---------------- fused: finalize1 + h2 = BN(t2) in place + h3 = tanh(h2 @ Wfc) ----------------
__global__ __launch_bounds__(256) void fc_kernel(float* __restrict__ io,
        const double* __restrict__ dsum, const double* __restrict__ dsq,
        const float* __restrict__ g, const float* __restrict__ b,
        const float* __restrict__ W) {
    __shared__ __align__(16) float u_s[64][DIM + 4];
    __shared__ __align__(16) float w_s[DIM][DIM + 4];
    __shared__ float sc_s[DIM], sh_s[DIM];
    const int t = threadIdx.x;
    const int row0 = blockIdx.x * 64;
    bn_fold_rep<DIM>(t, dsum, dsq, g, b, sc_s, sh_s);
    __syncthreads();
    for (int i = t; i < DIM * DIM; i += 256) {
        int k = i >> 6, c = i & 63;
        w_s[c][k] = W[i];
    }
    for (int i = t; i < 64 * DIM; i += 256) {
        int r = i >> 6, k = i & 63;
        int rr = row0 + r;
        float v = 0.f;
        if (rr < NN) {
            size_t idx = (size_t)rr * 192 + 64 + k;
            v = fmaf(io[idx], sc_s[k], sh_s[k]);
            io[idx] = v;                       // h2
        }
        u_s[r][k] = v;
    }
    __syncthreads();
    const int cc = t & 15;
    const int r0 = (t >> 4) << 2;
    float acc[4][4];
    #pragma unroll
    for (int j = 0; j < 4; j++) { acc[0][j] = 0.f; acc[1][j] = 0.f; acc[2][j] = 0.f; acc[3][j] = 0.f; }
    #pragma unroll 4
    for (int k = 0; k < DIM; k += 4) {
        float4 w0 = *(const float4*)&w_s[cc][k];
        float4 w1 = *(const float4*)&w_s[cc + 16][k];
        float4 w2 = *(const float4*)&w_s[cc + 32][k];
        float4 w3 = *(const float4*)&w_s[cc + 48][k];
        #pragma unroll
        for (int i = 0; i < 4; i++) {
            float4 u = *(const float4*)&u_s[r0 + i][k];
            acc[i][0] = fmaf(u.x, w0.x, fmaf(u.y, w0.y, fmaf(u.z, w0.z, fmaf(u.w, w0.w, acc[i][0]))));
            acc[i][1] = fmaf(u.x, w1.x, fmaf(u.y, w1.y, fmaf(u.z, w1.z, fmaf(u.w, w1.w, acc[i][1]))));
            acc[i][2] = fmaf(u.x, w2.x, fmaf(u.y, w2.y, fmaf(u.z, w2.z, fmaf(u.w, w2.w, acc[i][2]))));
            acc[i][3] = fmaf(u.x, w3.x, fmaf(u.y, w3.y, fmaf(u.z, w3.z, fmaf(u.w, w3.w, acc[i][3]))));
        }
    }
    #pragma unroll
    for (int i = 0; i < 4; i++) {
        int rr = row0 + r0 + i;
        if (rr < NN) {
            #pragma unroll
            for (int j = 0; j < 4; j++)
                io[(size_t)rr * 192 + 128 + cc + 16 * j] = tanhf(acc[i][j]);
        }
    }
}

extern "C" void kernel_launch(void* const* d_in, const int* in_sizes, int n_in,
                              void* d_out, int out_size, void* d_ws, size_t ws_size,
                              hipStream_t stream) {
    const float* X      = (const float*)d_in[0];
    const int*   ei     = (const int*)  d_in[1];
    const float* ea     = (const float*)d_in[2];
    const float* bng    = (const float*)d_in[3];
    const float* bnb    = (const float*)d_in[4];
    const float* We0    = (const float*)d_in[5];
    const float* be0    = (const float*)d_in[6];
    const float* W0     = (const float*)d_in[7];
    const float* b0     = (const float*)d_in[8];
    const float* bn0g   = (const float*)d_in[9];
    const float* bn0b   = (const float*)d_in[10];
    const float* We1    = (const float*)d_in[11];
    const float* be1    = (const float*)d_in[12];
    const float* W1     = (const float*)d_in[13];
    const float* b1     = (const float*)d_in[14];
    const float* bn1g   = (const float*)d_in[15];
    const float* bn1b   = (const float*)d_in[16];
    const float* Wfc    = (const float*)d_in[17];

    const int* src = ei;
    const int* dst = ei + NE;
    float* out = (float*)d_out;

    // ---- workspace layout (~65 MB) ----
    int2*   src_ea  = (int2*)d_ws;                       // NE
    float*  t1_ws   = (float*)(src_ea + NE);             // NN*DIM
    __half* Xh      = (__half*)(t1_ws + (size_t)NN * DIM); // NN*INC halves
    int*    counts  = (int*)(Xh + (size_t)NN * INC);     // NN
    int*    offs    = counts + NN;                       // NN+1
    int*    cursor  = offs + NN + 1;                     // NN
    int*    bsums   = cursor + NN;                       // 128
    double* dstats = (double*)(((uintptr_t)(bsums + 128) + 15) & ~(uintptr_t)15);
    double* dsum_in = dstats;                          // NREP*128
    double* dsq_in  = dsum_in + NREP * INC;            // NREP*128
    double* dsum0   = dsq_in + NREP * INC;             // NREP*64
    double* dsq0    = dsum0 + NREP * DIM;              // NREP*64
    double* dsum1   = dsq0 + NREP * DIM;               // NREP*64
    double* dsq1    = dsum1 + NREP * DIM;              // NREP*64
    const size_t nstats = (size_t)NREP * (2 * INC + 4 * DIM);

    hipMemsetAsync(counts, 0, NN * sizeof(int), stream);
    hipMemsetAsync(dstats, 0, nstats * sizeof(double), stream);

    // fused input-BN stats + dst histogram
    stats_hist_kernel<<<SB + (NE + 255) / 256, 256, 0, stream>>>(X, dst, counts, dsum_in, dsq_in);

    // x̂ -> fp16 (depends only on stats)
    xhat_half_kernel<<<(NN * INC / 4 + 255) / 256, 256, 0, stream>>>(X, dsum_in, dsq_in, bng, bnb, Xh);

    // CSR build (shared by both layers)
    const int NB = (NN + 1023) / 1024;   // 98
    scan1_kernel<<<NB, 1024, 0, stream>>>(counts, offs, bsums);
    scan2_kernel<<<1, 128, 0, stream>>>(bsums, NB);
    scan3_kernel<<<(NN + 255) / 256, 256, 0, stream>>>(offs, bsums, cursor);
    scatter_kernel<<<NE / 256, 256, 0, stream>>>(src, dst, ea, cursor, src_ea);

    // layer 0 (fused agg + GEMM + stats0), gathers fp16 x̂
    gine0_kernel<<<(NN + 31) / 32, 512, 0, stream>>>(X, Xh, offs, src_ea, dsum_in, dsq_in, bng, bnb,
                                                     We0, be0, W0, b0, t1_ws, dsum0, dsq0);

    // layer 1 (fused finalize0 + BN-on-fly + h1 write + agg + GEMM + stats1)
    gine1_kernel<<<(NN + 63) / 64, 512, 0, stream>>>(t1_ws, offs, src_ea, dsum0, dsq0, bn0g, bn0b,
                                                     We1, be1, W1, b1, out, dsum1, dsq1);

    // h2 (in place) + h3 (fused finalize1)
    fc_kernel<<<(NN + 63) / 64, 256, 0, stream>>>(out, dsum1, dsq1, bn1g, bn1b, Wfc);
}

// Round 9
// 479.996 us; speedup vs baseline: 1.8261x; 1.0343x over previous
//
#include <hip/hip_runtime.h>
#include <hip/hip_fp16.h>
#include <math.h>
#include <stdint.h>

#define NN 100000
#define NE 1600000
#define INC 128
#define DIM 64
#define EPS 1e-5f
#define SB 512   // stats blocks inside fused stats+hist kernel
#define NREP 8   // stats accumulator replicas (atomic-contention spreading)

struct __align__(8)  half4 { __half2 a, b; };
struct __align__(16) half8 { __half2 a, b, c, d; };

// fused: blocks [0,SB) do X stats (C=128) in f64; blocks [SB,...) do dst histogram
__global__ __launch_bounds__(256) void stats_hist_kernel(const float* __restrict__ X,
        const int* __restrict__ dst, int* __restrict__ counts,
        double* __restrict__ sum_out, double* __restrict__ sq_out) {
    __shared__ double ls[256], lq[256];
    if (blockIdx.x < SB) {
        int c  = threadIdx.x & 127;
        int rl = threadIdx.x >> 7;           // 2 rows per block step
        int row = blockIdx.x * 2 + rl;
        const int rstride = SB * 2;
        double s = 0.0, q = 0.0;
        for (int r = row; r < NN; r += rstride) {
            double v = (double)X[(size_t)r * INC + c];
            s += v; q += v * v;
        }
        ls[threadIdx.x] = s; lq[threadIdx.x] = q;
        __syncthreads();
        if (rl == 0) {
            s += ls[128 + c]; q += lq[128 + c];
            int rep = blockIdx.x & (NREP - 1);
            atomicAdd(&sum_out[rep * INC + c], s);
            atomicAdd(&sq_out[rep * INC + c], q);
        }
    } else {
        int e = (blockIdx.x - SB) * 256 + threadIdx.x;
        if (e < NE) atomicAdd(&counts[dst[e]], 1);
    }
}

// BN scale/shift from NREP-replicated f64 stats
template<int C>
__device__ inline void bn_fold_rep(int t, const double* dsum, const double* dsq,
                                   const float* g, const float* b, float* sc_s, float* sh_s) {
    if (t < C) {
        double s = 0.0, q = 0.0;
        #pragma unroll
        for (int r = 0; r < NREP; r++) { s += dsum[r * C + t]; q += dsq[r * C + t]; }
        double m = s / (double)NN;
        double v = q / (double)NN - m * m;
        double sc = (double)g[t] / sqrt(v + (double)EPS);
        sc_s[t] = (float)sc;
        sh_s[t] = (float)((double)b[t] - m * sc);
    }
}

// x̂ = BN(X) precomputed to fp16 [NN][128]
__global__ __launch_bounds__(256) void xhat_half_kernel(const float* __restrict__ X,
        const double* __restrict__ dsum, const double* __restrict__ dsq,
        const float* __restrict__ g, const float* __restrict__ b,
        __half* __restrict__ Xh) {
    __shared__ float sc_s[INC], sh_s[INC];
    bn_fold_rep<INC>(threadIdx.x, dsum, dsq, g, b, sc_s, sh_s);
    __syncthreads();
    size_t i = (size_t)blockIdx.x * 256 + threadIdx.x;   // one float4 per thread
    size_t e4 = i * 4;
    if (e4 >= (size_t)NN * INC) return;
    int c = (int)(e4 & 127);
    float4 x = *(const float4*)(X + e4);
    half4 h;
    h.a = __floats2half2_rn(fmaf(x.x, sc_s[c], sh_s[c]), fmaf(x.y, sc_s[c + 1], sh_s[c + 1]));
    h.b = __floats2half2_rn(fmaf(x.z, sc_s[c + 2], sh_s[c + 2]), fmaf(x.w, sc_s[c + 3], sh_s[c + 3]));
    *(half4*)(Xh + e4) = h;
}

// ---------------- CSR build: scan ----------------
__global__ __launch_bounds__(1024) void scan1_kernel(const int* __restrict__ counts,
                                                     int* __restrict__ offs, int* __restrict__ bsums) {
    __shared__ int tmp[2][1024];
    int t = threadIdx.x;
    int g = blockIdx.x * 1024 + t;
    int v = (g < NN) ? counts[g] : 0;
    tmp[0][t] = v;
    __syncthreads();
    int pin = 0;
    for (int d = 1; d < 1024; d <<= 1) {
        int x = tmp[pin][t] + ((t >= d) ? tmp[pin][t - d] : 0);
        tmp[pin ^ 1][t] = x;
        pin ^= 1;
        __syncthreads();
    }
    int incl = tmp[pin][t];
    if (g < NN) offs[g] = incl - v;
    if (t == 1023) bsums[blockIdx.x] = incl;
}

__global__ __launch_bounds__(128) void scan2_kernel(int* __restrict__ bsums, int nb) {
    __shared__ int tmp[2][128];
    int t = threadIdx.x;
    int v = (t < nb) ? bsums[t] : 0;
    tmp[0][t] = v;
    __syncthreads();
    int pin = 0;
    for (int d = 1; d < 128; d <<= 1) {
        int x = tmp[pin][t] + ((t >= d) ? tmp[pin][t - d] : 0);
        tmp[pin ^ 1][t] = x;
        pin ^= 1;
        __syncthreads();
    }
    if (t < nb) bsums[t] = tmp[pin][t] - v;
}

// final offsets + per-node scatter cursors
__global__ __launch_bounds__(256) void scan3_kernel(int* __restrict__ offs, const int* __restrict__ bsums,
                                                    int* __restrict__ cursor) {
    int g = blockIdx.x * 256 + threadIdx.x;
    if (g < NN) {
        int o = offs[g] + bsums[g >> 10];
        offs[g] = o;
        cursor[g] = o;
    }
    if (g == 0) offs[NN] = NE;
}

// direct scatter: one 8B store per edge, 100K cursors (low contention, ~16 edges/node)
__global__ __launch_bounds__(256) void scatter_kernel(const int* __restrict__ src, const int* __restrict__ dst,
                                                      const float* __restrict__ ea, int* __restrict__ cursor,
                                                      int2* __restrict__ src_ea) {
    int e = blockIdx.x * 256 + threadIdx.x;
    if (e >= NE) return;
    int d = dst[e];
    int pos = atomicAdd(&cursor[d], 1);
    src_ea[pos] = make_int2(src[e], __float_as_int(ea[e]));
}

// ---------------- fused layer 0: gather-agg (fp16 x̂, quarter-wave) + GEMM + tanh + stats ----------------
// 32 nodes per 512-thread block. t1 -> t1h [NN][64] fp16; per-channel stats -> dsum0/dsq0 (replicated)
__global__ __launch_bounds__(512) void gine0_kernel(const float* __restrict__ X,
        const __half* __restrict__ Xh,
        const int* __restrict__ offs, const int2* __restrict__ src_ea,
        const double* __restrict__ dsum, const double* __restrict__ dsq,
        const float* __restrict__ g, const float* __restrict__ b,
        const float* __restrict__ We, const float* __restrict__ be,
        const float* __restrict__ W, const float* __restrict__ bvec,
        __half* __restrict__ t1h, double* __restrict__ dsum0, double* __restrict__ dsq0) {
    __shared__ __align__(16) float u_s[32][INC + 4];   // 16.9 KB
    __shared__ __align__(16) float w_s[DIM][INC + 4];  // 33.8 KB (reused for stats reduce)
    __shared__ float sc_s[INC], sh_s[INC];
    const int t = threadIdx.x;
    const int row0 = blockIdx.x * 32;
    bn_fold_rep<INC>(t, dsum, dsq, g, b, sc_s, sh_s);
    for (int i = t; i < INC * DIM; i += 512) {
        int k = i >> 6, c = i & 63;
        w_s[c][k] = W[i];
    }
    __syncthreads();
    // gather: 8 waves x 4 nodes; wave split into 4 quarters of 16 lanes, each handles one edge
    const int wid = t >> 6, l = t & 63;
    const int quarter = l >> 4;
    const int c8 = (l & 15) * 8;
    float4 wv0 = *(const float4*)(We + c8);
    float4 wv1 = *(const float4*)(We + c8 + 4);
    float4 bv0 = *(const float4*)(be + c8);
    float4 bv1 = *(const float4*)(be + c8 + 4);
    for (int nn = 0; nn < 4; ++nn) {
        int r = wid * 4 + nn;
        int n = row0 + r;
        float a0 = 0.f, a1 = 0.f, a2 = 0.f, a3 = 0.f, a4 = 0.f, a5 = 0.f, a6 = 0.f, a7 = 0.f;
        if (n < NN) {
            int beg = offs[n], end = offs[n + 1];
            for (int base = beg; base < end; base += 64) {
                int j = base + l;
                int2 p = (j < end) ? src_ea[j] : make_int2(0, 0);
                float avf = __int_as_float(p.y);
                int cnt = min(64, end - base);
                int tt = 0;
                for (; tt + 8 <= cnt; tt += 8) {
                    int e0 = tt + quarter, e1 = tt + 4 + quarter;
                    int s0 = __shfl(p.x, e0), s1 = __shfl(p.x, e1);
                    float av0 = __shfl(avf, e0), av1 = __shfl(avf, e1);
                    half8 v0 = *(const half8*)(Xh + (size_t)s0 * INC + c8);
                    half8 v1 = *(const half8*)(Xh + (size_t)s1 * INC + c8);
                    float2 f0 = __half22float2(v0.a), f1 = __half22float2(v0.b);
                    float2 f2 = __half22float2(v0.c), f3 = __half22float2(v0.d);
                    a0 += fmaxf(f0.x + fmaf(av0, wv0.x, bv0.x), 0.f);
                    a1 += fmaxf(f0.y + fmaf(av0, wv0.y, bv0.y), 0.f);
                    a2 += fmaxf(f1.x + fmaf(av0, wv0.z, bv0.z), 0.f);
                    a3 += fmaxf(f1.y + fmaf(av0, wv0.w, bv0.w), 0.f);
                    a4 += fmaxf(f2.x + fmaf(av0, wv1.x, bv1.x), 0.f);
                    a5 += fmaxf(f2.y + fmaf(av0, wv1.y, bv1.y), 0.f);
                    a6 += fmaxf(f3.x + fmaf(av0, wv1.z, bv1.z), 0.f);
                    a7 += fmaxf(f3.y + fmaf(av0, wv1.w, bv1.w), 0.f);
                    f0 = __half22float2(v1.a); f1 = __half22float2(v1.b);
                    f2 = __half22float2(v1.c); f3 = __half22float2(v1.d);
                    a0 += fmaxf(f0.x + fmaf(av1, wv0.x, bv0.x), 0.f);
                    a1 += fmaxf(f0.y + fmaf(av1, wv0.y, bv0.y), 0.f);
                    a2 += fmaxf(f1.x + fmaf(av1, wv0.z, bv0.z), 0.f);
                    a3 += fmaxf(f1.y + fmaf(av1, wv0.w, bv0.w), 0.f);
                    a4 += fmaxf(f2.x + fmaf(av1, wv1.x, bv1.x), 0.f);
                    a5 += fmaxf(f2.y + fmaf(av1, wv1.y, bv1.y), 0.f);
                    a6 += fmaxf(f3.x + fmaf(av1, wv1.z, bv1.z), 0.f);
                    a7 += fmaxf(f3.y + fmaf(av1, wv1.w, bv1.w), 0.f);
                }
                for (; tt < cnt; tt += 4) {
                    int e0 = tt + quarter;
                    int es = min(e0, cnt - 1);
                    int s0 = __shfl(p.x, es);
                    float av0 = __shfl(avf, es);
                    if (e0 < cnt) {
                        half8 v0 = *(const half8*)(Xh + (size_t)s0 * INC + c8);
                        float2 f0 = __half22float2(v0.a), f1 = __half22float2(v0.b);
                        float2 f2 = __half22float2(v0.c), f3 = __half22float2(v0.d);
                        a0 += fmaxf(f0.x + fmaf(av0, wv0.x, bv0.x), 0.f);
                        a1 += fmaxf(f0.y + fmaf(av0, wv0.y, bv0.y), 0.f);
                        a2 += fmaxf(f1.x + fmaf(av0, wv0.z, bv0.z), 0.f);
                        a3 += fmaxf(f1.y + fmaf(av0, wv0.w, bv0.w), 0.f);
                        a4 += fmaxf(f2.x + fmaf(av0, wv1.x, bv1.x), 0.f);
                        a5 += fmaxf(f2.y + fmaf(av0, wv1.y, bv1.y), 0.f);
                        a6 += fmaxf(f3.x + fmaf(av0, wv1.z, bv1.z), 0.f);
                        a7 += fmaxf(f3.y + fmaf(av0, wv1.w, bv1.w), 0.f);
                    }
                }
            }
        }
        // combine quarters
        a0 += __shfl_xor(a0, 16); a0 += __shfl_xor(a0, 32);
        a1 += __shfl_xor(a1, 16); a1 += __shfl_xor(a1, 32);
        a2 += __shfl_xor(a2, 16); a2 += __shfl_xor(a2, 32);
        a3 += __shfl_xor(a3, 16); a3 += __shfl_xor(a3, 32);
        a4 += __shfl_xor(a4, 16); a4 += __shfl_xor(a4, 32);
        a5 += __shfl_xor(a5, 16); a5 += __shfl_xor(a5, 32);
        a6 += __shfl_xor(a6, 16); a6 += __shfl_xor(a6, 32);
        a7 += __shfl_xor(a7, 16); a7 += __shfl_xor(a7, 32);
        if (quarter == 0) {
            if (n < NN) {
                // self term from f32 X for precision
                float4 x0 = *(const float4*)(X + (size_t)n * INC + c8);
                float4 x1 = *(const float4*)(X + (size_t)n * INC + c8 + 4);
                a0 += fmaf(x0.x, sc_s[c8],     sh_s[c8]);
                a1 += fmaf(x0.y, sc_s[c8 + 1], sh_s[c8 + 1]);
                a2 += fmaf(x0.z, sc_s[c8 + 2], sh_s[c8 + 2]);
                a3 += fmaf(x0.w, sc_s[c8 + 3], sh_s[c8 + 3]);
                a4 += fmaf(x1.x, sc_s[c8 + 4], sh_s[c8 + 4]);
                a5 += fmaf(x1.y, sc_s[c8 + 5], sh_s[c8 + 5]);
                a6 += fmaf(x1.z, sc_s[c8 + 6], sh_s[c8 + 6]);
                a7 += fmaf(x1.w, sc_s[c8 + 7], sh_s[c8 + 7]);
            }
            *(float4*)&u_s[r][c8]     = make_float4(a0, a1, a2, a3);
            *(float4*)&u_s[r][c8 + 4] = make_float4(a4, a5, a6, a7);
        }
    }
    __syncthreads();
    // GEMM: 32x64 outputs, 512 threads -> 4 outputs each
    const int cc = t & 15;
    const int rg = t >> 4;                 // row 0..31
    float acc0 = bvec[cc], acc1 = bvec[cc + 16], acc2 = bvec[cc + 32], acc3 = bvec[cc + 48];
    #pragma unroll 4
    for (int k = 0; k < INC; k += 4) {
        float4 w0 = *(const float4*)&w_s[cc][k];
        float4 w1 = *(const float4*)&w_s[cc + 16][k];
        float4 w2 = *(const float4*)&w_s[cc + 32][k];
        float4 w3 = *(const float4*)&w_s[cc + 48][k];
        float4 u = *(const float4*)&u_s[rg][k];
        acc0 = fmaf(u.x, w0.x, fmaf(u.y, w0.y, fmaf(u.z, w0.z, fmaf(u.w, w0.w, acc0))));
        acc1 = fmaf(u.x, w1.x, fmaf(u.y, w1.y, fmaf(u.z, w1.z, fmaf(u.w, w1.w, acc1))));
        acc2 = fmaf(u.x, w2.x, fmaf(u.y, w2.y, fmaf(u.z, w2.z, fmaf(u.w, w2.w, acc2))));
        acc3 = fmaf(u.x, w3.x, fmaf(u.y, w3.y, fmaf(u.z, w3.z, fmaf(u.w, w3.w, acc3))));
    }
    int rr = row0 + rg;
    float t0 = tanhf(acc0), t1v = tanhf(acc1), t2v = tanhf(acc2), t3v = tanhf(acc3);
    if (rr < NN) {
        __half* op = t1h + (size_t)rr * DIM;
        op[cc]      = __float2half_rn(t0);
        op[cc + 16] = __float2half_rn(t1v);
        op[cc + 32] = __float2half_rn(t2v);
        op[cc + 48] = __float2half_rn(t3v);
    }
    // fused per-channel stats from f32 values (reuse w_s as [32 rows][64 cols] x2)
    __syncthreads();
    float* red_s = (float*)w_s;
    float* red_q = red_s + 2048;
    bool ok = (rr < NN);
    red_s[rg * 64 + cc]      = ok ? t0 : 0.f;
    red_s[rg * 64 + cc + 16] = ok ? t1v : 0.f;
    red_s[rg * 64 + cc + 32] = ok ? t2v : 0.f;
    red_s[rg * 64 + cc + 48] = ok ? t3v : 0.f;
    red_q[rg * 64 + cc]      = ok ? t0 * t0 : 0.f;
    red_q[rg * 64 + cc + 16] = ok ? t1v * t1v : 0.f;
    red_q[rg * 64 + cc + 32] = ok ? t2v * t2v : 0.f;
    red_q[rg * 64 + cc + 48] = ok ? t3v * t3v : 0.f;
    __syncthreads();
    if (t < 64) {
        float s = 0.f, q = 0.f;
        #pragma unroll
        for (int i = 0; i < 32; i++) { s += red_s[i * 64 + t]; q += red_q[i * 64 + t]; }
        int rep = blockIdx.x & (NREP - 1);
        atomicAdd(&dsum0[rep * DIM + t], (double)s);
        atomicAdd(&dsq0[rep * DIM + t], (double)q);
    }
}

// ---------------- fused layer 1: BN(fp16 t1) on the fly + h1 write + gather-agg + GEMM + tanh + stats ----------------
// 64 nodes per 512-thread block. reads t1h fp16; h1 -> out[:,0:64]; t2 -> out[:,64:128]
__global__ __launch_bounds__(512) void gine1_kernel(const __half* __restrict__ t1h,
        const int* __restrict__ offs, const int2* __restrict__ src_ea,
        const double* __restrict__ dsum, const double* __restrict__ dsq,
        const float* __restrict__ g, const float* __restrict__ b,
        const float* __restrict__ We, const float* __restrict__ be,
        const float* __restrict__ W, const float* __restrict__ bvec,
        float* __restrict__ out, double* __restrict__ dsum1, double* __restrict__ dsq1) {
    __shared__ __align__(16) float u_s[64][DIM + 4];   // 17.4 KB
    __shared__ __align__(16) float w_s[DIM][DIM + 4];  // 17.4 KB (reused for stats reduce)
    __shared__ float sc_s[DIM], sh_s[DIM];
    const int t = threadIdx.x;
    const int row0 = blockIdx.x * 64;
    bn_fold_rep<DIM>(t, dsum, dsq, g, b, sc_s, sh_s);
    for (int i = t; i < DIM * DIM; i += 512) {
        int k = i >> 6, c = i & 63;
        w_s[c][k] = W[i];
    }
    __syncthreads();
    const int wid = t >> 6, l = t & 63;
    const int quarter = l >> 4;
    const int c4 = (l & 15) * 4;
    float4 wv = *(const float4*)(We + c4);
    float4 bv = *(const float4*)(be + c4);
    float4 sc4 = *(const float4*)(sc_s + c4);
    float4 sh4 = *(const float4*)(sh_s + c4);
    for (int nn = 0; nn < 8; ++nn) {
        int r = wid * 8 + nn;
        int n = row0 + r;
        float a0 = 0.f, a1 = 0.f, a2 = 0.f, a3 = 0.f;
        if (n < NN) {
            int beg = offs[n], end = offs[n + 1];
            for (int base = beg; base < end; base += 64) {
                int j = base + l;
                int2 p = (j < end) ? src_ea[j] : make_int2(0, 0);
                float avf = __int_as_float(p.y);
                int cnt = min(64, end - base);
                int tt = 0;
                for (; tt + 8 <= cnt; tt += 8) {
                    int e0 = tt + quarter, e1 = tt + 4 + quarter;
                    int s0 = __shfl(p.x, e0), s1 = __shfl(p.x, e1);
                    float av0 = __shfl(avf, e0), av1 = __shfl(avf, e1);
                    half4 v0 = *(const half4*)(t1h + (size_t)s0 * DIM + c4);
                    half4 v1 = *(const half4*)(t1h + (size_t)s1 * DIM + c4);
                    float2 f00 = __half22float2(v0.a), f01 = __half22float2(v0.b);
                    float2 f10 = __half22float2(v1.a), f11 = __half22float2(v1.b);
                    a0 += fmaxf(fmaf(f00.x, sc4.x, sh4.x) + fmaf(av0, wv.x, bv.x), 0.f);
                    a1 += fmaxf(fmaf(f00.y, sc4.y, sh4.y) + fmaf(av0, wv.y, bv.y), 0.f);
                    a2 += fmaxf(fmaf(f01.x, sc4.z, sh4.z) + fmaf(av0, wv.z, bv.z), 0.f);
                    a3 += fmaxf(fmaf(f01.y, sc4.w, sh4.w) + fmaf(av0, wv.w, bv.w), 0.f);
                    a0 += fmaxf(fmaf(f10.x, sc4.x, sh4.x) + fmaf(av1, wv.x, bv.x), 0.f);
                    a1 += fmaxf(fmaf(f10.y, sc4.y, sh4.y) + fmaf(av1, wv.y, bv.y), 0.f);
                    a2 += fmaxf(fmaf(f11.x, sc4.z, sh4.z) + fmaf(av1, wv.z, bv.z), 0.f);
                    a3 += fmaxf(fmaf(f11.y, sc4.w, sh4.w) + fmaf(av1, wv.w, bv.w), 0.f);
                }
                for (; tt < cnt; tt += 4) {
                    int e0 = tt + quarter;
                    int es = min(e0, cnt - 1);
                    int s0 = __shfl(p.x, es);
                    float av0 = __shfl(avf, es);
                    if (e0 < cnt) {
                        half4 v0 = *(const half4*)(t1h + (size_t)s0 * DIM + c4);
                        float2 f00 = __half22float2(v0.a), f01 = __half22float2(v0.b);
                        a0 += fmaxf(fmaf(f00.x, sc4.x, sh4.x) + fmaf(av0, wv.x, bv.x), 0.f);
                        a1 += fmaxf(fmaf(f00.y, sc4.y, sh4.y) + fmaf(av0, wv.y, bv.y), 0.f);
                        a2 += fmaxf(fmaf(f01.x, sc4.z, sh4.z) + fmaf(av0, wv.z, bv.z), 0.f);
                        a3 += fmaxf(fmaf(f01.y, sc4.w, sh4.w) + fmaf(av0, wv.w, bv.w), 0.f);
                    }
                }
            }
        }
        a0 += __shfl_xor(a0, 16); a0 += __shfl_xor(a0, 32);
        a1 += __shfl_xor(a1, 16); a1 += __shfl_xor(a1, 32);
        a2 += __shfl_xor(a2, 16); a2 += __shfl_xor(a2, 32);
        a3 += __shfl_xor(a3, 16); a3 += __shfl_xor(a3, 32);
        if (quarter == 0) {
            if (n < NN) {
                half4 h = *(const half4*)(t1h + (size_t)n * DIM + c4);
                float2 f0 = __half22float2(h.a), f1 = __half22float2(h.b);
                float h0 = fmaf(f0.x, sc4.x, sh4.x);
                float h1 = fmaf(f0.y, sc4.y, sh4.y);
                float h2 = fmaf(f1.x, sc4.z, sh4.z);
                float h3 = fmaf(f1.y, sc4.w, sh4.w);
                *(float4*)(out + (size_t)n * 192 + c4) = make_float4(h0, h1, h2, h3);   // h1
                a0 += h0; a1 += h1; a2 += h2; a3 += h3;
            }
            *(float4*)&u_s[r][c4] = make_float4(a0, a1, a2, a3);
        }
    }
    __syncthreads();
    // GEMM: 64x64 outputs, 512 threads -> 8 outputs each (2 rows x 4 cols)
    const int cc = t & 15;
    const int r0 = (t >> 4) * 2;
    float acc[2][4];
    #pragma unroll
    for (int j = 0; j < 4; j++) {
        float bj = bvec[cc + 16 * j];
        acc[0][j] = bj; acc[1][j] = bj;
    }
    #pragma unroll 4
    for (int k = 0; k < DIM; k += 4) {
        float4 w0 = *(const float4*)&w_s[cc][k];
        float4 w1 = *(const float4*)&w_s[cc + 16][k];
        float4 w2 = *(const float4*)&w_s[cc + 32][k];
        float4 w3 = *(const float4*)&w_s[cc + 48][k];
        #pragma unroll
        for (int i = 0; i < 2; i++) {
            float4 u = *(const float4*)&u_s[r0 + i][k];
            acc[i][0] = fmaf(u.x, w0.x, fmaf(u.y, w0.y, fmaf(u.z, w0.z, fmaf(u.w, w0.w, acc[i][0]))));
            acc[i][1] = fmaf(u.x, w1.x, fmaf(u.y, w1.y, fmaf(u.z, w1.z, fmaf(u.w, w1.w, acc[i][1]))));
            acc[i][2] = fmaf(u.x, w2.x, fmaf(u.y, w2.y, fmaf(u.z, w2.z, fmaf(u.w, w2.w, acc[i][2]))));
            acc[i][3] = fmaf(u.x, w3.x, fmaf(u.y, w3.y, fmaf(u.z, w3.z, fmaf(u.w, w3.w, acc[i][3]))));
        }
    }
    float tv[2][4];
    #pragma unroll
    for (int i = 0; i < 2; i++) {
        int rr = row0 + r0 + i;
        #pragma unroll
        for (int j = 0; j < 4; j++) tv[i][j] = tanhf(acc[i][j]);
        if (rr < NN) {
            float* op = out + (size_t)rr * 192 + 64;
            #pragma unroll
            for (int j = 0; j < 4; j++) op[cc + 16 * j] = tv[i][j];
        }
    }
    // fused per-channel stats of t2 (reuse w_s as [32 rowgrps][64 cols] x2)
    __syncthreads();
    float* red_s = (float*)w_s;
    float* red_q = red_s + 2048;
    const int rgp = t >> 4;
    bool ok0 = (row0 + r0 < NN), ok1 = (row0 + r0 + 1 < NN);
    #pragma unroll
    for (int j = 0; j < 4; j++) {
        float v0 = ok0 ? tv[0][j] : 0.f;
        float v1 = ok1 ? tv[1][j] : 0.f;
        red_s[rgp * 64 + cc + 16 * j] = v0 + v1;
        red_q[rgp * 64 + cc + 16 * j] = v0 * v0 + v1 * v1;
    }
    __syncthreads();
    if (t < 64) {
        float s = 0.f, q = 0.f;
        #pragma unroll
        for (int i = 0; i < 32; i++) { s += red_s[i * 64 + t]; q += red_q[i * 64 + t]; }
        int rep = blockIdx.x & (NREP - 1);
        atomicAdd(&dsum1[rep * DIM + t], (double)s);
        atomicAdd(&dsq1[rep * DIM + t], (double)q);
    }
}

// ---------------- fused: finalize1 + h2 = BN(t2) in place + h3 = tanh(h2 @ Wfc) ----------------
__global__ __launch_bounds__(256) void fc_kernel(float* __restrict__ io,
        const double* __restrict__ dsum, const double* __restrict__ dsq,
        const float* __restrict__ g, const float* __restrict__ b,
        const float* __restrict__ W) {
    __shared__ __align__(16) float u_s[64][DIM + 4];
    __shared__ __align__(16) float w_s[DIM][DIM + 4];
    __shared__ float sc_s[DIM], sh_s[DIM];
    const int t = threadIdx.x;
    const int row0 = blockIdx.x * 64;
    bn_fold_rep<DIM>(t, dsum, dsq, g, b, sc_s, sh_s);
    __syncthreads();
    for (int i = t; i < DIM * DIM; i += 256) {
        int k = i >> 6, c = i & 63;
        w_s[c][k] = W[i];
    }
    for (int i = t; i < 64 * DIM; i += 256) {
        int r = i >> 6, k = i & 63;
        int rr = row0 + r;
        float v = 0.f;
        if (rr < NN) {
            size_t idx = (size_t)rr * 192 + 64 + k;
            v = fmaf(io[idx], sc_s[k], sh_s[k]);
            io[idx] = v;                       // h2
        }
        u_s[r][k] = v;
    }
    __syncthreads();
    const int cc = t & 15;
    const int r0 = (t >> 4) << 2;
    float acc[4][4];
    #pragma unroll
    for (int j = 0; j < 4; j++) { acc[0][j] = 0.f; acc[1][j] = 0.f; acc[2][j] = 0.f; acc[3][j] = 0.f; }
    #pragma unroll 4
    for (int k = 0; k < DIM; k += 4) {
        float4 w0 = *(const float4*)&w_s[cc][k];
        float4 w1 = *(const float4*)&w_s[cc + 16][k];
        float4 w2 = *(const float4*)&w_s[cc + 32][k];
        float4 w3 = *(const float4*)&w_s[cc + 48][k];
        #pragma unroll
        for (int i = 0; i < 4; i++) {
            float4 u = *(const float4*)&u_s[r0 + i][k];
            acc[i][0] = fmaf(u.x, w0.x, fmaf(u.y, w0.y, fmaf(u.z, w0.z, fmaf(u.w, w0.w, acc[i][0]))));
            acc[i][1] = fmaf(u.x, w1.x, fmaf(u.y, w1.y, fmaf(u.z, w1.z, fmaf(u.w, w1.w, acc[i][1]))));
            acc[i][2] = fmaf(u.x, w2.x, fmaf(u.y, w2.y, fmaf(u.z, w2.z, fmaf(u.w, w2.w, acc[i][2]))));
            acc[i][3] = fmaf(u.x, w3.x, fmaf(u.y, w3.y, fmaf(u.z, w3.z, fmaf(u.w, w3.w, acc[i][3]))));
        }
    }
    #pragma unroll
    for (int i = 0; i < 4; i++) {
        int rr = row0 + r0 + i;
        if (rr < NN) {
            #pragma unroll
            for (int j = 0; j < 4; j++)
                io[(size_t)rr * 192 + 128 + cc + 16 * j] = tanhf(acc[i][j]);
        }
    }
}

extern "C" void kernel_launch(void* const* d_in, const int* in_sizes, int n_in,
                              void* d_out, int out_size, void* d_ws, size_t ws_size,
                              hipStream_t stream) {
    const float* X      = (const float*)d_in[0];
    const int*   ei     = (const int*)  d_in[1];
    const float* ea     = (const float*)d_in[2];
    const float* bng    = (const float*)d_in[3];
    const float* bnb    = (const float*)d_in[4];
    const float* We0    = (const float*)d_in[5];
    const float* be0    = (const float*)d_in[6];
    const float* W0     = (const float*)d_in[7];
    const float* b0     = (const float*)d_in[8];
    const float* bn0g   = (const float*)d_in[9];
    const float* bn0b   = (const float*)d_in[10];
    const float* We1    = (const float*)d_in[11];
    const float* be1    = (const float*)d_in[12];
    const float* W1     = (const float*)d_in[13];
    const float* b1     = (const float*)d_in[14];
    const float* bn1g   = (const float*)d_in[15];
    const float* bn1b   = (const float*)d_in[16];
    const float* Wfc    = (const float*)d_in[17];

    const int* src = ei;
    const int* dst = ei + NE;
    float* out = (float*)d_out;

    // ---- workspace layout (~52 MB) ----
    int2*   src_ea  = (int2*)d_ws;                        // NE
    __half* t1h     = (__half*)(src_ea + NE);             // NN*DIM halves
    __half* Xh      = t1h + (size_t)NN * DIM;             // NN*INC halves
    int*    counts  = (int*)(Xh + (size_t)NN * INC);      // NN
    int*    offs    = counts + NN;                        // NN+1
    int*    cursor  = offs + NN + 1;                      // NN
    int*    bsums   = cursor + NN;                        // 128
    double* dstats = (double*)(((uintptr_t)(bsums + 128) + 15) & ~(uintptr_t)15);
    double* dsum_in = dstats;                          // NREP*128
    double* dsq_in  = dsum_in + NREP * INC;            // NREP*128
    double* dsum0   = dsq_in + NREP * INC;             // NREP*64
    double* dsq0    = dsum0 + NREP * DIM;              // NREP*64
    double* dsum1   = dsq0 + NREP * DIM;               // NREP*64
    double* dsq1    = dsum1 + NREP * DIM;              // NREP*64
    const size_t nstats = (size_t)NREP * (2 * INC + 4 * DIM);

    hipMemsetAsync(counts, 0, NN * sizeof(int), stream);
    hipMemsetAsync(dstats, 0, nstats * sizeof(double), stream);

    // fused input-BN stats + dst histogram
    stats_hist_kernel<<<SB + (NE + 255) / 256, 256, 0, stream>>>(X, dst, counts, dsum_in, dsq_in);

    // x̂ -> fp16 (depends only on stats)
    xhat_half_kernel<<<(NN * INC / 4 + 255) / 256, 256, 0, stream>>>(X, dsum_in, dsq_in, bng, bnb, Xh);

    // CSR build (shared by both layers)
    const int NB = (NN + 1023) / 1024;   // 98
    scan1_kernel<<<NB, 1024, 0, stream>>>(counts, offs, bsums);
    scan2_kernel<<<1, 128, 0, stream>>>(bsums, NB);
    scan3_kernel<<<(NN + 255) / 256, 256, 0, stream>>>(offs, bsums, cursor);
    scatter_kernel<<<NE / 256, 256, 0, stream>>>(src, dst, ea, cursor, src_ea);

    // layer 0 (fused agg + GEMM + stats0), gathers fp16 x̂, writes fp16 t1
    gine0_kernel<<<(NN + 31) / 32, 512, 0, stream>>>(X, Xh, offs, src_ea, dsum_in, dsq_in, bng, bnb,
                                                     We0, be0, W0, b0, t1h, dsum0, dsq0);

    // layer 1 (fused finalize0 + BN-on-fly + h1 write + agg + GEMM + stats1), gathers fp16 t1
    gine1_kernel<<<(NN + 63) / 64, 512, 0, stream>>>(t1h, offs, src_ea, dsum0, dsq0, bn0g, bn0b,
                                                     We1, be1, W1, b1, out, dsum1, dsq1);

    // h2 (in place) + h3 (fused finalize1)
    fc_kernel<<<(NN + 63) / 64, 256, 0, stream>>>(out, dsum1, dsq1, bn1g, bn1b, Wfc);
}

// Round 10
// 440.696 us; speedup vs baseline: 1.9890x; 1.0892x over previous
//
#include <hip/hip_runtime.h>
#include <hip/hip_fp16.h>
#include <math.h>
#include <stdint.h>

#define NN 100000
#define NE 1600000
#define INC 128
#define DIM 64
#define EPS 1e-5f
#define SB 512    // stats blocks inside fused stats+hist kernel
#define NREP 8    // stats accumulator replicas (atomic-contention spreading)
#define NPART 8   // scatter partitions (~1 per XCD; write set 12.8MB/8 = 1.6MB < 4MB L2)
#define PART_SZ ((NN + NPART - 1) / NPART)

struct __align__(8)  half4 { __half2 a, b; };
struct __align__(16) half8 { __half2 a, b, c, d; };

// fused: blocks [0,SB) do X stats (C=128) in f64; blocks [SB,...) do dst histogram
__global__ __launch_bounds__(256) void stats_hist_kernel(const float* __restrict__ X,
        const int* __restrict__ dst, int* __restrict__ counts,
        double* __restrict__ sum_out, double* __restrict__ sq_out) {
    __shared__ double ls[256], lq[256];
    if (blockIdx.x < SB) {
        int c  = threadIdx.x & 127;
        int rl = threadIdx.x >> 7;           // 2 rows per block step
        int row = blockIdx.x * 2 + rl;
        const int rstride = SB * 2;
        double s = 0.0, q = 0.0;
        for (int r = row; r < NN; r += rstride) {
            double v = (double)X[(size_t)r * INC + c];
            s += v; q += v * v;
        }
        ls[threadIdx.x] = s; lq[threadIdx.x] = q;
        __syncthreads();
        if (rl == 0) {
            s += ls[128 + c]; q += lq[128 + c];
            int rep = blockIdx.x & (NREP - 1);
            atomicAdd(&sum_out[rep * INC + c], s);
            atomicAdd(&sq_out[rep * INC + c], q);
        }
    } else {
        int e = (blockIdx.x - SB) * 256 + threadIdx.x;
        if (e < NE) atomicAdd(&counts[dst[e]], 1);
    }
}

// BN scale/shift from NREP-replicated f64 stats
template<int C>
__device__ inline void bn_fold_rep(int t, const double* dsum, const double* dsq,
                                   const float* g, const float* b, float* sc_s, float* sh_s) {
    if (t < C) {
        double s = 0.0, q = 0.0;
        #pragma unroll
        for (int r = 0; r < NREP; r++) { s += dsum[r * C + t]; q += dsq[r * C + t]; }
        double m = s / (double)NN;
        double v = q / (double)NN - m * m;
        double sc = (double)g[t] / sqrt(v + (double)EPS);
        sc_s[t] = (float)sc;
        sh_s[t] = (float)((double)b[t] - m * sc);
    }
}

// x̂ = BN(X) precomputed to fp16 [NN][128]
__global__ __launch_bounds__(256) void xhat_half_kernel(const float* __restrict__ X,
        const double* __restrict__ dsum, const double* __restrict__ dsq,
        const float* __restrict__ g, const float* __restrict__ b,
        __half* __restrict__ Xh) {
    __shared__ float sc_s[INC], sh_s[INC];
    bn_fold_rep<INC>(threadIdx.x, dsum, dsq, g, b, sc_s, sh_s);
    __syncthreads();
    size_t i = (size_t)blockIdx.x * 256 + threadIdx.x;   // one float4 per thread
    size_t e4 = i * 4;
    if (e4 >= (size_t)NN * INC) return;
    int c = (int)(e4 & 127);
    float4 x = *(const float4*)(X + e4);
    half4 h;
    h.a = __floats2half2_rn(fmaf(x.x, sc_s[c], sh_s[c]), fmaf(x.y, sc_s[c + 1], sh_s[c + 1]));
    h.b = __floats2half2_rn(fmaf(x.z, sc_s[c + 2], sh_s[c + 2]), fmaf(x.w, sc_s[c + 3], sh_s[c + 3]));
    *(half4*)(Xh + e4) = h;
}

// ---------------- CSR build: scan ----------------
__global__ __launch_bounds__(1024) void scan1_kernel(const int* __restrict__ counts,
                                                     int* __restrict__ offs, int* __restrict__ bsums) {
    __shared__ int tmp[2][1024];
    int t = threadIdx.x;
    int g = blockIdx.x * 1024 + t;
    int v = (g < NN) ? counts[g] : 0;
    tmp[0][t] = v;
    __syncthreads();
    int pin = 0;
    for (int d = 1; d < 1024; d <<= 1) {
        int x = tmp[pin][t] + ((t >= d) ? tmp[pin][t - d] : 0);
        tmp[pin ^ 1][t] = x;
        pin ^= 1;
        __syncthreads();
    }
    int incl = tmp[pin][t];
    if (g < NN) offs[g] = incl - v;
    if (t == 1023) bsums[blockIdx.x] = incl;
}

__global__ __launch_bounds__(128) void scan2_kernel(int* __restrict__ bsums, int nb) {
    __shared__ int tmp[2][128];
    int t = threadIdx.x;
    int v = (t < nb) ? bsums[t] : 0;
    tmp[0][t] = v;
    __syncthreads();
    int pin = 0;
    for (int d = 1; d < 128; d <<= 1) {
        int x = tmp[pin][t] + ((t >= d) ? tmp[pin][t - d] : 0);
        tmp[pin ^ 1][t] = x;
        pin ^= 1;
        __syncthreads();
    }
    if (t < nb) bsums[t] = tmp[pin][t] - v;
}

// final offsets + per-node scatter cursors
__global__ __launch_bounds__(256) void scan3_kernel(int* __restrict__ offs, const int* __restrict__ bsums,
                                                    int* __restrict__ cursor) {
    int g = blockIdx.x * 256 + threadIdx.x;
    if (g < NN) {
        int o = offs[g] + bsums[g >> 10];
        offs[g] = o;
        cursor[g] = o;
    }
    if (g == 0) offs[NN] = NE;
}

// XCD-partitioned scatter: blocks with blockIdx&7==p handle dst in partition p.
// Each partition's CSR slice is contiguous (~1.6MB) -> write working set fits one L2.
__global__ __launch_bounds__(256) void scatter_kernel(const int* __restrict__ src, const int* __restrict__ dst,
                                                      const float* __restrict__ ea, int* __restrict__ cursor,
                                                      int2* __restrict__ src_ea) {
    const int p = blockIdx.x & (NPART - 1);      // heuristic: maps to XCD via round-robin dispatch
    const int blk = blockIdx.x >> 3;
    const int nblk = gridDim.x >> 3;
    const int lo = p * PART_SZ;
    const int hi = min(NN, lo + PART_SZ);
    for (int e = blk * 256 + threadIdx.x; e < NE; e += nblk * 256) {
        int d = dst[e];
        if (d >= lo && d < hi) {
            int pos = atomicAdd(&cursor[d], 1);
            src_ea[pos] = make_int2(src[e], __float_as_int(ea[e]));
        }
    }
}

// ---------------- fused layer 0: gather-agg (fp16 x̂, quarter-wave) + GEMM + tanh + stats ----------------
// 32 nodes per 512-thread block. t1 -> t1h [NN][64] fp16; per-channel stats -> dsum0/dsq0 (replicated)
__global__ __launch_bounds__(512) void gine0_kernel(const float* __restrict__ X,
        const __half* __restrict__ Xh,
        const int* __restrict__ offs, const int2* __restrict__ src_ea,
        const double* __restrict__ dsum, const double* __restrict__ dsq,
        const float* __restrict__ g, const float* __restrict__ b,
        const float* __restrict__ We, const float* __restrict__ be,
        const float* __restrict__ W, const float* __restrict__ bvec,
        __half* __restrict__ t1h, double* __restrict__ dsum0, double* __restrict__ dsq0) {
    __shared__ __align__(16) float u_s[32][INC + 4];   // 16.9 KB
    __shared__ __align__(16) float w_s[DIM][INC + 4];  // 33.8 KB (reused for stats reduce)
    __shared__ float sc_s[INC], sh_s[INC];
    const int t = threadIdx.x;
    const int row0 = blockIdx.x * 32;
    bn_fold_rep<INC>(t, dsum, dsq, g, b, sc_s, sh_s);
    for (int i = t; i < INC * DIM; i += 512) {
        int k = i >> 6, c = i & 63;
        w_s[c][k] = W[i];
    }
    __syncthreads();
    // gather: 8 waves x 4 nodes; wave split into 4 quarters of 16 lanes, each handles one edge
    const int wid = t >> 6, l = t & 63;
    const int quarter = l >> 4;
    const int c8 = (l & 15) * 8;
    float4 wv0 = *(const float4*)(We + c8);
    float4 wv1 = *(const float4*)(We + c8 + 4);
    float4 bv0 = *(const float4*)(be + c8);
    float4 bv1 = *(const float4*)(be + c8 + 4);
    for (int nn = 0; nn < 4; ++nn) {
        int r = wid * 4 + nn;
        int n = row0 + r;
        float a0 = 0.f, a1 = 0.f, a2 = 0.f, a3 = 0.f, a4 = 0.f, a5 = 0.f, a6 = 0.f, a7 = 0.f;
        if (n < NN) {
            int beg = offs[n], end = offs[n + 1];
            for (int base = beg; base < end; base += 64) {
                int j = base + l;
                int2 p = (j < end) ? src_ea[j] : make_int2(0, 0);
                float avf = __int_as_float(p.y);
                int cnt = min(64, end - base);
                int tt = 0;
                for (; tt + 8 <= cnt; tt += 8) {
                    int e0 = tt + quarter, e1 = tt + 4 + quarter;
                    int s0 = __shfl(p.x, e0), s1 = __shfl(p.x, e1);
                    float av0 = __shfl(avf, e0), av1 = __shfl(avf, e1);
                    half8 v0 = *(const half8*)(Xh + (size_t)s0 * INC + c8);
                    half8 v1 = *(const half8*)(Xh + (size_t)s1 * INC + c8);
                    float2 f0 = __half22float2(v0.a), f1 = __half22float2(v0.b);
                    float2 f2 = __half22float2(v0.c), f3 = __half22float2(v0.d);
                    a0 += fmaxf(f0.x + fmaf(av0, wv0.x, bv0.x), 0.f);
                    a1 += fmaxf(f0.y + fmaf(av0, wv0.y, bv0.y), 0.f);
                    a2 += fmaxf(f1.x + fmaf(av0, wv0.z, bv0.z), 0.f);
                    a3 += fmaxf(f1.y + fmaf(av0, wv0.w, bv0.w), 0.f);
                    a4 += fmaxf(f2.x + fmaf(av0, wv1.x, bv1.x), 0.f);
                    a5 += fmaxf(f2.y + fmaf(av0, wv1.y, bv1.y), 0.f);
                    a6 += fmaxf(f3.x + fmaf(av0, wv1.z, bv1.z), 0.f);
                    a7 += fmaxf(f3.y + fmaf(av0, wv1.w, bv1.w), 0.f);
                    f0 = __half22float2(v1.a); f1 = __half22float2(v1.b);
                    f2 = __half22float2(v1.c); f3 = __half22float2(v1.d);
                    a0 += fmaxf(f0.x + fmaf(av1, wv0.x, bv0.x), 0.f);
                    a1 += fmaxf(f0.y + fmaf(av1, wv0.y, bv0.y), 0.f);
                    a2 += fmaxf(f1.x + fmaf(av1, wv0.z, bv0.z), 0.f);
                    a3 += fmaxf(f1.y + fmaf(av1, wv0.w, bv0.w), 0.f);
                    a4 += fmaxf(f2.x + fmaf(av1, wv1.x, bv1.x), 0.f);
                    a5 += fmaxf(f2.y + fmaf(av1, wv1.y, bv1.y), 0.f);
                    a6 += fmaxf(f3.x + fmaf(av1, wv1.z, bv1.z), 0.f);
                    a7 += fmaxf(f3.y + fmaf(av1, wv1.w, bv1.w), 0.f);
                }
                for (; tt < cnt; tt += 4) {
                    int e0 = tt + quarter;
                    int es = min(e0, cnt - 1);
                    int s0 = __shfl(p.x, es);
                    float av0 = __shfl(avf, es);
                    if (e0 < cnt) {
                        half8 v0 = *(const half8*)(Xh + (size_t)s0 * INC + c8);
                        float2 f0 = __half22float2(v0.a), f1 = __half22float2(v0.b);
                        float2 f2 = __half22float2(v0.c), f3 = __half22float2(v0.d);
                        a0 += fmaxf(f0.x + fmaf(av0, wv0.x, bv0.x), 0.f);
                        a1 += fmaxf(f0.y + fmaf(av0, wv0.y, bv0.y), 0.f);
                        a2 += fmaxf(f1.x + fmaf(av0, wv0.z, bv0.z), 0.f);
                        a3 += fmaxf(f1.y + fmaf(av0, wv0.w, bv0.w), 0.f);
                        a4 += fmaxf(f2.x + fmaf(av0, wv1.x, bv1.x), 0.f);
                        a5 += fmaxf(f2.y + fmaf(av0, wv1.y, bv1.y), 0.f);
                        a6 += fmaxf(f3.x + fmaf(av0, wv1.z, bv1.z), 0.f);
                        a7 += fmaxf(f3.y + fmaf(av0, wv1.w, bv1.w), 0.f);
                    }
                }
            }
        }
        // combine quarters
        a0 += __shfl_xor(a0, 16); a0 += __shfl_xor(a0, 32);
        a1 += __shfl_xor(a1, 16); a1 += __shfl_xor(a1, 32);
        a2 += __shfl_xor(a2, 16); a2 += __shfl_xor(a2, 32);
        a3 += __shfl_xor(a3, 16); a3 += __shfl_xor(a3, 32);
        a4 += __shfl_xor(a4, 16); a4 += __shfl_xor(a4, 32);
        a5 += __shfl_xor(a5, 16); a5 += __shfl_xor(a5, 32);
        a6 += __shfl_xor(a6, 16); a6 += __shfl_xor(a6, 32);
        a7 += __shfl_xor(a7, 16); a7 += __shfl_xor(a7, 32);
        if (quarter == 0) {
            if (n < NN) {
                // self term from f32 X for precision
                float4 x0 = *(const float4*)(X + (size_t)n * INC + c8);
                float4 x1 = *(const float4*)(X + (size_t)n * INC + c8 + 4);
                a0 += fmaf(x0.x, sc_s[c8],     sh_s[c8]);
                a1 += fmaf(x0.y, sc_s[c8 + 1], sh_s[c8 + 1]);
                a2 += fmaf(x0.z, sc_s[c8 + 2], sh_s[c8 + 2]);
                a3 += fmaf(x0.w, sc_s[c8 + 3], sh_s[c8 + 3]);
                a4 += fmaf(x1.x, sc_s[c8 + 4], sh_s[c8 + 4]);
                a5 += fmaf(x1.y, sc_s[c8 + 5], sh_s[c8 + 5]);
                a6 += fmaf(x1.z, sc_s[c8 + 6], sh_s[c8 + 6]);
                a7 += fmaf(x1.w, sc_s[c8 + 7], sh_s[c8 + 7]);
            }
            *(float4*)&u_s[r][c8]     = make_float4(a0, a1, a2, a3);
            *(float4*)&u_s[r][c8 + 4] = make_float4(a4, a5, a6, a7);
        }
    }
    __syncthreads();
    // GEMM: 32x64 outputs, 512 threads -> 4 outputs each
    const int cc = t & 15;
    const int rg = t >> 4;                 // row 0..31
    float acc0 = bvec[cc], acc1 = bvec[cc + 16], acc2 = bvec[cc + 32], acc3 = bvec[cc + 48];
    #pragma unroll 4
    for (int k = 0; k < INC; k += 4) {
        float4 w0 = *(const float4*)&w_s[cc][k];
        float4 w1 = *(const float4*)&w_s[cc + 16][k];
        float4 w2 = *(const float4*)&w_s[cc + 32][k];
        float4 w3 = *(const float4*)&w_s[cc + 48][k];
        float4 u = *(const float4*)&u_s[rg][k];
        acc0 = fmaf(u.x, w0.x, fmaf(u.y, w0.y, fmaf(u.z, w0.z, fmaf(u.w, w0.w, acc0))));
        acc1 = fmaf(u.x, w1.x, fmaf(u.y, w1.y, fmaf(u.z, w1.z, fmaf(u.w, w1.w, acc1))));
        acc2 = fmaf(u.x, w2.x, fmaf(u.y, w2.y, fmaf(u.z, w2.z, fmaf(u.w, w2.w, acc2))));
        acc3 = fmaf(u.x, w3.x, fmaf(u.y, w3.y, fmaf(u.z, w3.z, fmaf(u.w, w3.w, acc3))));
    }
    int rr = row0 + rg;
    float t0 = tanhf(acc0), t1v = tanhf(acc1), t2v = tanhf(acc2), t3v = tanhf(acc3);
    if (rr < NN) {
        __half* op = t1h + (size_t)rr * DIM;
        op[cc]      = __float2half_rn(t0);
        op[cc + 16] = __float2half_rn(t1v);
        op[cc + 32] = __float2half_rn(t2v);
        op[cc + 48] = __float2half_rn(t3v);
    }
    // fused per-channel stats from f32 values (reuse w_s as [32 rows][64 cols] x2)
    __syncthreads();
    float* red_s = (float*)w_s;
    float* red_q = red_s + 2048;
    bool ok = (rr < NN);
    red_s[rg * 64 + cc]      = ok ? t0 : 0.f;
    red_s[rg * 64 + cc + 16] = ok ? t1v : 0.f;
    red_s[rg * 64 + cc + 32] = ok ? t2v : 0.f;
    red_s[rg * 64 + cc + 48] = ok ? t3v : 0.f;
    red_q[rg * 64 + cc]      = ok ? t0 * t0 : 0.f;
    red_q[rg * 64 + cc + 16] = ok ? t1v * t1v : 0.f;
    red_q[rg * 64 + cc + 32] = ok ? t2v * t2v : 0.f;
    red_q[rg * 64 + cc + 48] = ok ? t3v * t3v : 0.f;
    __syncthreads();
    if (t < 64) {
        float s = 0.f, q = 0.f;
        #pragma unroll
        for (int i = 0; i < 32; i++) { s += red_s[i * 64 + t]; q += red_q[i * 64 + t]; }
        int rep = blockIdx.x & (NREP - 1);
        atomicAdd(&dsum0[rep * DIM + t], (double)s);
        atomicAdd(&dsq0[rep * DIM + t], (double)q);
    }
}

// ---------------- fused layer 1: BN(fp16 t1) on the fly + h1 write + gather-agg + GEMM + tanh + stats ----------------
// 64 nodes per 512-thread block. reads t1h fp16; h1 -> out[:,0:64]; t2 -> out[:,64:128]
__global__ __launch_bounds__(512) void gine1_kernel(const __half* __restrict__ t1h,
        const int* __restrict__ offs, const int2* __restrict__ src_ea,
        const double* __restrict__ dsum, const double* __restrict__ dsq,
        const float* __restrict__ g, const float* __restrict__ b,
        const float* __restrict__ We, const float* __restrict__ be,
        const float* __restrict__ W, const float* __restrict__ bvec,
        float* __restrict__ out, double* __restrict__ dsum1, double* __restrict__ dsq1) {
    __shared__ __align__(16) float u_s[64][DIM + 4];   // 17.4 KB
    __shared__ __align__(16) float w_s[DIM][DIM + 4];  // 17.4 KB (reused for stats reduce)
    __shared__ float sc_s[DIM], sh_s[DIM];
    const int t = threadIdx.x;
    const int row0 = blockIdx.x * 64;
    bn_fold_rep<DIM>(t, dsum, dsq, g, b, sc_s, sh_s);
    for (int i = t; i < DIM * DIM; i += 512) {
        int k = i >> 6, c = i & 63;
        w_s[c][k] = W[i];
    }
    __syncthreads();
    const int wid = t >> 6, l = t & 63;
    const int quarter = l >> 4;
    const int c4 = (l & 15) * 4;
    float4 wv = *(const float4*)(We + c4);
    float4 bv = *(const float4*)(be + c4);
    float4 sc4 = *(const float4*)(sc_s + c4);
    float4 sh4 = *(const float4*)(sh_s + c4);
    for (int nn = 0; nn < 8; ++nn) {
        int r = wid * 8 + nn;
        int n = row0 + r;
        float a0 = 0.f, a1 = 0.f, a2 = 0.f, a3 = 0.f;
        if (n < NN) {
            int beg = offs[n], end = offs[n + 1];
            for (int base = beg; base < end; base += 64) {
                int j = base + l;
                int2 p = (j < end) ? src_ea[j] : make_int2(0, 0);
                float avf = __int_as_float(p.y);
                int cnt = min(64, end - base);
                int tt = 0;
                for (; tt + 8 <= cnt; tt += 8) {
                    int e0 = tt + quarter, e1 = tt + 4 + quarter;
                    int s0 = __shfl(p.x, e0), s1 = __shfl(p.x, e1);
                    float av0 = __shfl(avf, e0), av1 = __shfl(avf, e1);
                    half4 v0 = *(const half4*)(t1h + (size_t)s0 * DIM + c4);
                    half4 v1 = *(const half4*)(t1h + (size_t)s1 * DIM + c4);
                    float2 f00 = __half22float2(v0.a), f01 = __half22float2(v0.b);
                    float2 f10 = __half22float2(v1.a), f11 = __half22float2(v1.b);
                    a0 += fmaxf(fmaf(f00.x, sc4.x, sh4.x) + fmaf(av0, wv.x, bv.x), 0.f);
                    a1 += fmaxf(fmaf(f00.y, sc4.y, sh4.y) + fmaf(av0, wv.y, bv.y), 0.f);
                    a2 += fmaxf(fmaf(f01.x, sc4.z, sh4.z) + fmaf(av0, wv.z, bv.z), 0.f);
                    a3 += fmaxf(fmaf(f01.y, sc4.w, sh4.w) + fmaf(av0, wv.w, bv.w), 0.f);
                    a0 += fmaxf(fmaf(f10.x, sc4.x, sh4.x) + fmaf(av1, wv.x, bv.x), 0.f);
                    a1 += fmaxf(fmaf(f10.y, sc4.y, sh4.y) + fmaf(av1, wv.y, bv.y), 0.f);
                    a2 += fmaxf(fmaf(f11.x, sc4.z, sh4.z) + fmaf(av1, wv.z, bv.z), 0.f);
                    a3 += fmaxf(fmaf(f11.y, sc4.w, sh4.w) + fmaf(av1, wv.w, bv.w), 0.f);
                }
                for (; tt < cnt; tt += 4) {
                    int e0 = tt + quarter;
                    int es = min(e0, cnt - 1);
                    int s0 = __shfl(p.x, es);
                    float av0 = __shfl(avf, es);
                    if (e0 < cnt) {
                        half4 v0 = *(const half4*)(t1h + (size_t)s0 * DIM + c4);
                        float2 f00 = __half22float2(v0.a), f01 = __half22float2(v0.b);
                        a0 += fmaxf(fmaf(f00.x, sc4.x, sh4.x) + fmaf(av0, wv.x, bv.x), 0.f);
                        a1 += fmaxf(fmaf(f00.y, sc4.y, sh4.y) + fmaf(av0, wv.y, bv.y), 0.f);
                        a2 += fmaxf(fmaf(f01.x, sc4.z, sh4.z) + fmaf(av0, wv.z, bv.z), 0.f);
                        a3 += fmaxf(fmaf(f01.y, sc4.w, sh4.w) + fmaf(av0, wv.w, bv.w), 0.f);
                    }
                }
            }
        }
        a0 += __shfl_xor(a0, 16); a0 += __shfl_xor(a0, 32);
        a1 += __shfl_xor(a1, 16); a1 += __shfl_xor(a1, 32);
        a2 += __shfl_xor(a2, 16); a2 += __shfl_xor(a2, 32);
        a3 += __shfl_xor(a3, 16); a3 += __shfl_xor(a3, 32);
        if (quarter == 0) {
            if (n < NN) {
                half4 h = *(const half4*)(t1h + (size_t)n * DIM + c4);
                float2 f0 = __half22float2(h.a), f1 = __half22float2(h.b);
                float h0 = fmaf(f0.x, sc4.x, sh4.x);
                float h1 = fmaf(f0.y, sc4.y, sh4.y);
                float h2 = fmaf(f1.x, sc4.z, sh4.z);
                float h3 = fmaf(f1.y, sc4.w, sh4.w);
                *(float4*)(out + (size_t)n * 192 + c4) = make_float4(h0, h1, h2, h3);   // h1
                a0 += h0; a1 += h1; a2 += h2; a3 += h3;
            }
            *(float4*)&u_s[r][c4] = make_float4(a0, a1, a2, a3);
        }
    }
    __syncthreads();
    // GEMM: 64x64 outputs, 512 threads -> 8 outputs each (2 rows x 4 cols)
    const int cc = t & 15;
    const int r0 = (t >> 4) * 2;
    float acc[2][4];
    #pragma unroll
    for (int j = 0; j < 4; j++) {
        float bj = bvec[cc + 16 * j];
        acc[0][j] = bj; acc[1][j] = bj;
    }
    #pragma unroll 4
    for (int k = 0; k < DIM; k += 4) {
        float4 w0 = *(const float4*)&w_s[cc][k];
        float4 w1 = *(const float4*)&w_s[cc + 16][k];
        float4 w2 = *(const float4*)&w_s[cc + 32][k];
        float4 w3 = *(const float4*)&w_s[cc + 48][k];
        #pragma unroll
        for (int i = 0; i < 2; i++) {
            float4 u = *(const float4*)&u_s[r0 + i][k];
            acc[i][0] = fmaf(u.x, w0.x, fmaf(u.y, w0.y, fmaf(u.z, w0.z, fmaf(u.w, w0.w, acc[i][0]))));
            acc[i][1] = fmaf(u.x, w1.x, fmaf(u.y, w1.y, fmaf(u.z, w1.z, fmaf(u.w, w1.w, acc[i][1]))));
            acc[i][2] = fmaf(u.x, w2.x, fmaf(u.y, w2.y, fmaf(u.z, w2.z, fmaf(u.w, w2.w, acc[i][2]))));
            acc[i][3] = fmaf(u.x, w3.x, fmaf(u.y, w3.y, fmaf(u.z, w3.z, fmaf(u.w, w3.w, acc[i][3]))));
        }
    }
    float tv[2][4];
    #pragma unroll
    for (int i = 0; i < 2; i++) {
        int rr = row0 + r0 + i;
        #pragma unroll
        for (int j = 0; j < 4; j++) tv[i][j] = tanhf(acc[i][j]);
        if (rr < NN) {
            float* op = out + (size_t)rr * 192 + 64;
            #pragma unroll
            for (int j = 0; j < 4; j++) op[cc + 16 * j] = tv[i][j];
        }
    }
    // fused per-channel stats of t2 (reuse w_s as [32 rowgrps][64 cols] x2)
    __syncthreads();
    float* red_s = (float*)w_s;
    float* red_q = red_s + 2048;
    const int rgp = t >> 4;
    bool ok0 = (row0 + r0 < NN), ok1 = (row0 + r0 + 1 < NN);
    #pragma unroll
    for (int j = 0; j < 4; j++) {
        float v0 = ok0 ? tv[0][j] : 0.f;
        float v1 = ok1 ? tv[1][j] : 0.f;
        red_s[rgp * 64 + cc + 16 * j] = v0 + v1;
        red_q[rgp * 64 + cc + 16 * j] = v0 * v0 + v1 * v1;
    }
    __syncthreads();
    if (t < 64) {
        float s = 0.f, q = 0.f;
        #pragma unroll
        for (int i = 0; i < 32; i++) { s += red_s[i * 64 + t]; q += red_q[i * 64 + t]; }
        int rep = blockIdx.x & (NREP - 1);
        atomicAdd(&dsum1[rep * DIM + t], (double)s);
        atomicAdd(&dsq1[rep * DIM + t], (double)q);
    }
}

// ---------------- fused: finalize1 + h2 = BN(t2) in place + h3 = tanh(h2 @ Wfc) ----------------
__global__ __launch_bounds__(256) void fc_kernel(float* __restrict__ io,
        const double* __restrict__ dsum, const double* __restrict__ dsq,
        const float* __restrict__ g, const float* __restrict__ b,
        const float* __restrict__ W) {
    __shared__ __align__(16) float u_s[64][DIM + 4];
    __shared__ __align__(16) float w_s[DIM][DIM + 4];
    __shared__ float sc_s[DIM], sh_s[DIM];
    const int t = threadIdx.x;
    const int row0 = blockIdx.x * 64;
    bn_fold_rep<DIM>(t, dsum, dsq, g, b, sc_s, sh_s);
    __syncthreads();
    for (int i = t; i < DIM * DIM; i += 256) {
        int k = i >> 6, c = i & 63;
        w_s[c][k] = W[i];
    }
    for (int i = t; i < 64 * DIM; i += 256) {
        int r = i >> 6, k = i & 63;
        int rr = row0 + r;
        float v = 0.f;
        if (rr < NN) {
            size_t idx = (size_t)rr * 192 + 64 + k;
            v = fmaf(io[idx], sc_s[k], sh_s[k]);
            io[idx] = v;                       // h2
        }
        u_s[r][k] = v;
    }
    __syncthreads();
    const int cc = t & 15;
    const int r0 = (t >> 4) << 2;
    float acc[4][4];
    #pragma unroll
    for (int j = 0; j < 4; j++) { acc[0][j] = 0.f; acc[1][j] = 0.f; acc[2][j] = 0.f; acc[3][j] = 0.f; }
    #pragma unroll 4
    for (int k = 0; k < DIM; k += 4) {
        float4 w0 = *(const float4*)&w_s[cc][k];
        float4 w1 = *(const float4*)&w_s[cc + 16][k];
        float4 w2 = *(const float4*)&w_s[cc + 32][k];
        float4 w3 = *(const float4*)&w_s[cc + 48][k];
        #pragma unroll
        for (int i = 0; i < 4; i++) {
            float4 u = *(const float4*)&u_s[r0 + i][k];
            acc[i][0] = fmaf(u.x, w0.x, fmaf(u.y, w0.y, fmaf(u.z, w0.z, fmaf(u.w, w0.w, acc[i][0]))));
            acc[i][1] = fmaf(u.x, w1.x, fmaf(u.y, w1.y, fmaf(u.z, w1.z, fmaf(u.w, w1.w, acc[i][1]))));
            acc[i][2] = fmaf(u.x, w2.x, fmaf(u.y, w2.y, fmaf(u.z, w2.z, fmaf(u.w, w2.w, acc[i][2]))));
            acc[i][3] = fmaf(u.x, w3.x, fmaf(u.y, w3.y, fmaf(u.z, w3.z, fmaf(u.w, w3.w, acc[i][3]))));
        }
    }
    #pragma unroll
    for (int i = 0; i < 4; i++) {
        int rr = row0 + r0 + i;
        if (rr < NN) {
            #pragma unroll
            for (int j = 0; j < 4; j++)
                io[(size_t)rr * 192 + 128 + cc + 16 * j] = tanhf(acc[i][j]);
        }
    }
}

extern "C" void kernel_launch(void* const* d_in, const int* in_sizes, int n_in,
                              void* d_out, int out_size, void* d_ws, size_t ws_size,
                              hipStream_t stream) {
    const float* X      = (const float*)d_in[0];
    const int*   ei     = (const int*)  d_in[1];
    const float* ea     = (const float*)d_in[2];
    const float* bng    = (const float*)d_in[3];
    const float* bnb    = (const float*)d_in[4];
    const float* We0    = (const float*)d_in[5];
    const float* be0    = (const float*)d_in[6];
    const float* W0     = (const float*)d_in[7];
    const float* b0     = (const float*)d_in[8];
    const float* bn0g   = (const float*)d_in[9];
    const float* bn0b   = (const float*)d_in[10];
    const float* We1    = (const float*)d_in[11];
    const float* be1    = (const float*)d_in[12];
    const float* W1     = (const float*)d_in[13];
    const float* b1     = (const float*)d_in[14];
    const float* bn1g   = (const float*)d_in[15];
    const float* bn1b   = (const float*)d_in[16];
    const float* Wfc    = (const float*)d_in[17];

    const int* src = ei;
    const int* dst = ei + NE;
    float* out = (float*)d_out;

    // ---- workspace layout (~52 MB) ----
    int2*   src_ea  = (int2*)d_ws;                        // NE
    __half* t1h     = (__half*)(src_ea + NE);             // NN*DIM halves
    __half* Xh      = t1h + (size_t)NN * DIM;             // NN*INC halves
    int*    counts  = (int*)(Xh + (size_t)NN * INC);      // NN
    int*    offs    = counts + NN;                        // NN+1
    int*    cursor  = offs + NN + 1;                      // NN
    int*    bsums   = cursor + NN;                        // 128
    double* dstats = (double*)(((uintptr_t)(bsums + 128) + 15) & ~(uintptr_t)15);
    double* dsum_in = dstats;                          // NREP*128
    double* dsq_in  = dsum_in + NREP * INC;            // NREP*128
    double* dsum0   = dsq_in + NREP * INC;             // NREP*64
    double* dsq0    = dsum0 + NREP * DIM;              // NREP*64
    double* dsum1   = dsq0 + NREP * DIM;               // NREP*64
    double* dsq1    = dsum1 + NREP * DIM;              // NREP*64
    const size_t nstats = (size_t)NREP * (2 * INC + 4 * DIM);

    hipMemsetAsync(counts, 0, NN * sizeof(int), stream);
    hipMemsetAsync(dstats, 0, nstats * sizeof(double), stream);

    // fused input-BN stats + dst histogram
    stats_hist_kernel<<<SB + (NE + 255) / 256, 256, 0, stream>>>(X, dst, counts, dsum_in, dsq_in);

    // x̂ -> fp16 (depends only on stats)
    xhat_half_kernel<<<(NN * INC / 4 + 255) / 256, 256, 0, stream>>>(X, dsum_in, dsq_in, bng, bnb, Xh);

    // CSR build (shared by both layers)
    const int NB = (NN + 1023) / 1024;   // 98
    scan1_kernel<<<NB, 1024, 0, stream>>>(counts, offs, bsums);
    scan2_kernel<<<1, 128, 0, stream>>>(bsums, NB);
    scan3_kernel<<<(NN + 255) / 256, 256, 0, stream>>>(offs, bsums, cursor);
    // XCD-partitioned scatter: 2048 blocks = 256 per partition
    scatter_kernel<<<2048, 256, 0, stream>>>(src, dst, ea, cursor, src_ea);

    // layer 0 (fused agg + GEMM + stats0), gathers fp16 x̂, writes fp16 t1
    gine0_kernel<<<(NN + 31) / 32, 512, 0, stream>>>(X, Xh, offs, src_ea, dsum_in, dsq_in, bng, bnb,
                                                     We0, be0, W0, b0, t1h, dsum0, dsq0);

    // layer 1 (fused finalize0 + BN-on-fly + h1 write + agg + GEMM + stats1), gathers fp16 t1
    gine1_kernel<<<(NN + 63) / 64, 512, 0, stream>>>(t1h, offs, src_ea, dsum0, dsq0, bn0g, bn0b,
                                                     We1, be1, W1, b1, out, dsum1, dsq1);

    // h2 (in place) + h3 (fused finalize1)
    fc_kernel<<<(NN + 63) / 64, 256, 0, stream>>>(out, dsum1, dsq1, bn1g, bn1b, Wfc);
}